// Round 14
// baseline (771.961 us; speedup 1.0000x reference)
//
#include <hip/hip_runtime.h>
#include <hip/hip_bf16.h>
#include <stdint.h>

// ---------- types ----------
typedef _Float16 half2v __attribute__((ext_vector_type(2)));
typedef _Float16 half8v __attribute__((ext_vector_type(8)));
typedef uint32_t u32x4  __attribute__((ext_vector_type(4)));
typedef float    f32x4  __attribute__((ext_vector_type(4)));

__device__ __forceinline__ unsigned short f2h(float f) {
  _Float16 h = (_Float16)f;
  return __builtin_bit_cast(unsigned short, h);
}
__device__ __forceinline__ half2v bch2(uint32_t u) {
  return __builtin_bit_cast(half2v, u);
}
__device__ __forceinline__ uint32_t pkrtz_u32(float a, float b) {
  return __builtin_bit_cast(uint32_t, __builtin_amdgcn_cvt_pkrtz(a, b));
}

// Window-major qkv layout (channel 0 of head n, pixel (h,w)).
__device__ __forceinline__ int qkv_idx(int half, int b, int n, int h, int w) {
  int idx = half * 8388608 + (b * 8 + n) * 131072;
  idx += (half == 0) ? ((h >> 3) * 16384 + w * 256 + (h & 7) * 32)
                     : (h * 2048 + w * 32);
  return idx;
}

// async global->LDS, 16 bytes per lane. lbase = wave-uniform base.
#define GLOAD_LDS16(gsrc, lbase)                                          \
  __builtin_amdgcn_global_load_lds(                                       \
      (const __attribute__((address_space(1))) uint32_t*)(gsrc),          \
      (__attribute__((address_space(3))) uint32_t*)(lbase), 16, 0, 0)

// ---------- f32 -> f16 conversion of x (4 elems/thread) ----------
__global__ __launch_bounds__(256) void cvt_f32_f16(const float* __restrict__ in,
                                                   unsigned short* __restrict__ out,
                                                   int n4) {
  int i = blockIdx.x * 256 + threadIdx.x;
  if (i >= n4) return;
  float4 f = reinterpret_cast<const float4*>(in)[i];
  ushort4 u;
  u.x = f2h(f.x); u.y = f2h(f.y); u.z = f2h(f.z); u.w = f2h(f.w);
  reinterpret_cast<ushort4*>(out)[i] = u;
}

// ---------- all weight casts in ONE launch ----------
__global__ __launch_bounds__(256) void cvt_weights(
    const float* __restrict__ wqkv, const float* __restrict__ wproj,
    const float* __restrict__ lh,   const float* __restrict__ lv,
    unsigned short* __restrict__ owqkv, unsigned short* __restrict__ owproj,
    unsigned short* __restrict__ owlep)
{
  int i = blockIdx.x * 256 + threadIdx.x;   // float4 index
  const float* src; unsigned short* dst; int off;
  if      (i < 196608) { src = wqkv;  dst = owqkv;        off = i; }
  else if (i < 262144) { src = wproj; dst = owproj;       off = i - 196608; }
  else if (i < 262720) { src = lh;    dst = owlep;        off = i - 262144; }
  else if (i < 263296) { src = lv;    dst = owlep + 2304; off = i - 262720; }
  else return;
  float4 f = reinterpret_cast<const float4*>(src)[off];
  ushort4 u;
  u.x = f2h(f.x); u.y = f2h(f.y); u.z = f2h(f.z); u.w = f2h(f.w);
  reinterpret_cast<ushort4*>(dst)[off] = u;
}

// ---------- 256^2 f16 GEMM, BK=32 dbuf (64KB LDS -> 2 blocks/CU) ----------
// C[m,n] = sum_k A[m,k]*B[n,k]; 512 thr = 8 waves (2M x 4N), wave tile 128x64,
// MFMA 16x16x32 operand-swapped. R7/R9-PROVEN sync skeleton: stage t+1 ->
// counted vmcnt(4) (never 0 in loop) -> s_barrier -> compute (12 ds_read_b128
// + 32 MFMA) -> s_barrier. 2 blocks/CU restore the cross-block TLP that hides
// the vmcnt/barrier waits (R9 mechanism) while 256^2 doubles FLOP per staged
// byte vs 128^2. Proven R9 swizzle formulas verbatim (2 lanes/bank = free).
// 1D grid + bijective XCD swizzle, n-fast in XCD chunk.
// MODE 0: f32 out + bias token-major. MODE 1: f16 scatter to qkv windows.
template<int MODE>
__global__ __launch_bounds__(512, 4) void gemm256(
    const unsigned short* __restrict__ A,
    const unsigned short* __restrict__ Bm,
    unsigned short* __restrict__ Cq,
    float* __restrict__ Cf,
    const float* __restrict__ bias,
    int M, int N)
{
  constexpr int K = 512;
  __shared__ unsigned short As[2][256 * 32];   // 2 x 16KB
  __shared__ unsigned short Bs[2][256 * 32];   // 2 x 16KB
  const int tid  = threadIdx.x;
  const int gn   = N >> 8;
  const int cpx  = gridDim.x >> 3;
  const int bid  = blockIdx.x;
  const int wgid = (bid & 7) * cpx + (bid >> 3);   // bijective (grid%8==0)
  const int m0   = (wgid / gn) * 256;
  const int n0   = (wgid % gn) * 256;
  const int wave = tid >> 6, lane = tid & 63;
  const int wr  = wave >> 2;        // 0..1 (128 M-rows)
  const int wcn = wave & 3;         // 0..3 (64 N-cols)
  // staging (R9 formulas): row sr (128/issue), pre-swizzled 16B chunk
  const int sr = tid >> 2;                                // 0..127
  const int sc = ((tid & 3) ^ ((tid >> 3) & 3)) * 8;
  const size_t aBase0 = (size_t)(m0 + sr) * K + sc;
  const size_t aBase1 = (size_t)(m0 + 128 + sr) * K + sc;
  const size_t bBase0 = (size_t)(n0 + sr) * K + sc;
  const size_t bBase1 = (size_t)(n0 + 128 + sr) * K + sc;
  char* ldsA = (char*)(&As[0][0]) + (tid & ~63) * 16;
  char* ldsB = (char*)(&Bs[0][0]) + (tid & ~63) * 16;

#define STAGE(bsel, kofs)                                           \
  do {                                                              \
    GLOAD_LDS16(A  + aBase0 + (kofs), ldsA + (bsel) * 16384);        \
    GLOAD_LDS16(A  + aBase1 + (kofs), ldsA + (bsel) * 16384 + 8192); \
    GLOAD_LDS16(Bm + bBase0 + (kofs), ldsB + (bsel) * 16384);        \
    GLOAD_LDS16(Bm + bBase1 + (kofs), ldsB + (bsel) * 16384 + 8192); \
  } while (0)

  STAGE(0, 0);

  f32x4 acc[8][4];
  const f32x4 zero = {0.f, 0.f, 0.f, 0.f};
  #pragma unroll
  for (int i = 0; i < 8; ++i)
    #pragma unroll
    for (int j = 0; j < 4; ++j) acc[i][j] = zero;

  const int lr   = lane & 15;
  const int slot = (lane >> 4) ^ ((lr >> 1) & 3);   // proven 2-way-free swizzle

  auto compute = [&](const unsigned short* Asb, const unsigned short* Bsb) {
    half8v bf[4];
    #pragma unroll
    for (int j = 0; j < 4; ++j)
      bf[j] = *reinterpret_cast<const half8v*>(Bsb + (wcn * 64 + j * 16 + lr) * 32 + slot * 8);
    half8v af[8];
    #pragma unroll
    for (int i = 0; i < 8; ++i)
      af[i] = *reinterpret_cast<const half8v*>(Asb + (wr * 128 + i * 16 + lr) * 32 + slot * 8);
    __builtin_amdgcn_s_setprio(1);
    #pragma unroll
    for (int i = 0; i < 8; ++i)
      #pragma unroll
      for (int j = 0; j < 4; ++j)
        acc[i][j] = __builtin_amdgcn_mfma_f32_16x16x32_f16(bf[j], af[i], acc[i][j], 0, 0, 0);
    __builtin_amdgcn_s_setprio(0);
  };

  const int nt = K >> 5;   // 16
  for (int t = 0; t < nt - 1; ++t) {
    STAGE((t + 1) & 1, (t + 1) * 32);                // issue next-tile loads
    asm volatile("s_waitcnt vmcnt(4)" ::: "memory"); // tile t landed; t+1 in flight
    __builtin_amdgcn_s_barrier();
    __builtin_amdgcn_sched_barrier(0);
    compute(&As[t & 1][0], &Bs[t & 1][0]);
    __builtin_amdgcn_s_barrier();                    // all done reading buf[t&1]
    __builtin_amdgcn_sched_barrier(0);
  }
  asm volatile("s_waitcnt vmcnt(0)" ::: "memory");
  __builtin_amdgcn_s_barrier();
  __builtin_amdgcn_sched_barrier(0);
  compute(&As[(nt - 1) & 1][0], &Bs[(nt - 1) & 1][0]);
#undef STAGE

  // D layout (operand-swapped): row(n) = (lane>>4)*4 + e, col(m) = lane&15
  const int cr = (lane >> 4) * 4;   // channel offset (4 contiguous)
  const int cc = lane & 15;         // token offset

  if constexpr (MODE == 0) {
    #pragma unroll
    for (int j = 0; j < 4; ++j) {
      const int n = n0 + wcn * 64 + j * 16 + cr;
      const float4 b4 = *reinterpret_cast<const float4*>(bias + n);
      #pragma unroll
      for (int i = 0; i < 8; ++i) {
        const int m = m0 + wr * 128 + i * 16 + cc;
        float4 r;
        r.x = acc[i][j][0] + b4.x;
        r.y = acc[i][j][1] + b4.y;
        r.z = acc[i][j][2] + b4.z;
        r.w = acc[i][j][3] + b4.w;
        *reinterpret_cast<float4*>(Cf + (size_t)m * N + n) = r;
      }
    }
  } else {
    const int mb   = m0 + wr * 128;   // token base (wave-uniform, 128-aligned)
    const int btok = mb >> 12;
    const int hr0  = (mb >> 6) & 63;  // wave spans h-rows hr0, hr0+1
    #pragma unroll
    for (int j = 0; j < 4; ++j) {
      const int nb    = n0 + wcn * 64 + j * 16 + cr;  // 4 contiguous channels
      const int tq    = nb >> 9;                      // 0=q 1=k 2=v
      const int halfc = (nb >> 8) & 1;
      const int nn    = (nb & 255) >> 5;
      const int ch4   = nb & 31;
      const int headbase = tq * 16777216 + halfc * 8388608 +
                           (btok * 8 + nn) * 131072 + ch4;
      #pragma unroll
      for (int i = 0; i < 8; ++i) {
        const int hrow = hr0 + (i >> 2);
        const int wpix = (i & 3) * 16 + cc;
        const int off = halfc ? (hrow * 2048 + wpix * 32)
                              : ((hrow >> 3) * 16384 + wpix * 256 + (hrow & 7) * 32);
        uint2 r;
        r.x = pkrtz_u32(acc[i][j][0], acc[i][j][1]);
        r.y = pkrtz_u32(acc[i][j][2], acc[i][j][3]);
        *reinterpret_cast<uint2*>(Cq + headbase + off) = r;
      }
    }
  }
}

// ---------- stripe attention + LePE, TWO windows per wave ----------
__global__ __launch_bounds__(256) void attn_lepe(
    const unsigned short* __restrict__ qkvp,
    const unsigned short* __restrict__ wlep,
    unsigned short* __restrict__ outp)
{
  const int gw   = (int)((blockIdx.x * 256 + threadIdx.x) >> 6);  // pair index
  const int lane = threadIdx.x & 63;
  const int half = gw >> 14;
  const int id   = gw & 16383;
  const int b    = id >> 11;
  const int n    = (id >> 8) & 7;
  int h0, w0;
  if (half == 0) { h0 = ((id >> 5) & 7) * 8; w0 = (id & 31) * 2; }
  else           { h0 = ((id >> 3) & 31) * 2; w0 = (id & 7) * 8; }
  const int baseA = qkv_idx(half, b, n, h0, w0);
  const int dWin  = (half == 0) ? 256 : 2048;
  const int baseB = baseA + dWin;

  // ---- QK^T for both windows: lane = (qr, kr) ----
  const int qr = lane >> 3, kr = lane & 7;
  const unsigned short* qA = qkvp + baseA + qr * 32;
  const unsigned short* kA = qkvp + 16777216 + baseA + kr * 32;
  float sA = 0.f, sB = 0.f;
  #pragma unroll
  for (int c = 0; c < 4; ++c) {
    const u32x4 qa = *reinterpret_cast<const u32x4*>(qA + c * 8);
    const u32x4 ka = *reinterpret_cast<const u32x4*>(kA + c * 8);
    const u32x4 qb = *reinterpret_cast<const u32x4*>(qA + dWin + c * 8);
    const u32x4 kb = *reinterpret_cast<const u32x4*>(kA + dWin + c * 8);
    #pragma unroll
    for (int e = 0; e < 4; ++e) {
      sA = __builtin_amdgcn_fdot2(bch2(qa[e]), bch2(ka[e]), sA, false);
      sB = __builtin_amdgcn_fdot2(bch2(qb[e]), bch2(kb[e]), sB, false);
    }
  }
  const float scl = 0.17677669529663687f;
  const float pA = __expf(sA * scl);
  const float pB = __expf(sB * scl);
  float denA = pA, denB = pB;
  denA += __shfl_xor(denA, 1); denA += __shfl_xor(denA, 2); denA += __shfl_xor(denA, 4);
  denB += __shfl_xor(denB, 1); denB += __shfl_xor(denB, 2); denB += __shfl_xor(denB, 4);
  const float aAv = pA * __builtin_amdgcn_rcpf(denA);
  const float aBv = pB * __builtin_amdgcn_rcpf(denB);
  const uint32_t adu = pkrtz_u32(aAv, aBv);   // lo = winA, hi = winB

  // ---- PV: lane = (qr2, win, dgrp); 16B vectors over 8 channels ----
  const int dgrp = lane & 3;
  const int win  = (lane >> 2) & 1;
  const int qr2  = lane >> 3;
  const int d0   = dgrp * 8;
  const int mybase = win ? baseB : baseA;
  const unsigned short* vwin = qkvp + 33554432 + mybase;

  half2v o01 = {0,0}, o23 = {0,0}, o45 = {0,0}, o67 = {0,0};
  #pragma unroll
  for (int k = 0; k < 8; ++k) {
    const uint32_t pairw = (uint32_t)__shfl((int)adu, qr2 * 8 + k);
    const half2v ph = bch2(pairw);
    const _Float16 av = win ? ph.y : ph.x;
    const half2v ak2 = {av, av};
    const u32x4 vv = *reinterpret_cast<const u32x4*>(vwin + k * 32 + d0);
    o01 += ak2 * bch2(vv[0]);
    o23 += ak2 * bch2(vv[1]);
    o45 += ak2 * bch2(vv[2]);
    o67 += ak2 * bch2(vv[3]);
  }

  // ---- LePE: depthwise 3x3 on v (zero-pad SAME) at this lane's pixel ----
  const int hq = (half == 0) ? (h0 + qr2) : (h0 + win);
  const int wq = (half == 0) ? (w0 + win) : (w0 + qr2);
  const unsigned short* vplane = qkvp + 33554432;
  const unsigned short* wl = wlep + half * 2304 + n * 32 + d0;
  half2v l01 = {0,0}, l23 = {0,0}, l45 = {0,0}, l67 = {0,0};
  #pragma unroll
  for (int dy = -1; dy <= 1; ++dy) {
    #pragma unroll
    for (int dx = -1; dx <= 1; ++dx) {
      const int hh = hq + dy, ww = wq + dx;
      u32x4 vv = {0u, 0u, 0u, 0u};
      if ((unsigned)hh < 64u && (unsigned)ww < 64u)
        vv = *reinterpret_cast<const u32x4*>(vplane + qkv_idx(half, b, n, hh, ww) + d0);
      const u32x4 wt = *reinterpret_cast<const u32x4*>(wl + ((dy + 1) * 3 + dx + 1) * 256);
      l01 += bch2(wt[0]) * bch2(vv[0]);
      l23 += bch2(wt[1]) * bch2(vv[1]);
      l45 += bch2(wt[2]) * bch2(vv[2]);
      l67 += bch2(wt[3]) * bch2(vv[3]);
    }
  }

  // ---- store token-major for GEMM2 (16B per lane) ----
  const int m = b * 4096 + hq * 64 + wq;
  const int chan0 = half * 256 + n * 32;
  u32x4 r;
  r[0] = __builtin_bit_cast(uint32_t, (half2v)(o01 + l01));
  r[1] = __builtin_bit_cast(uint32_t, (half2v)(o23 + l23));
  r[2] = __builtin_bit_cast(uint32_t, (half2v)(o45 + l45));
  r[3] = __builtin_bit_cast(uint32_t, (half2v)(o67 + l67));
  *reinterpret_cast<u32x4*>(outp + (size_t)m * 512 + chan0 + d0) = r;
}

// ---------- launch ----------
extern "C" void kernel_launch(void* const* d_in, const int* in_sizes, int n_in,
                              void* d_out, int out_size, void* d_ws, size_t ws_size,
                              hipStream_t stream) {
  const float* x      = (const float*)d_in[0];   // (8, 4096, 512)
  const float* w_qkv  = (const float*)d_in[1];   // (1536, 512)
  const float* w_proj = (const float*)d_in[2];   // (512, 512)
  const float* b_proj = (const float*)d_in[3];   // (512,)
  const float* lepe_h = (const float*)d_in[4];   // (3,3,1,256)
  const float* lepe_v = (const float*)d_in[5];   // (3,3,1,256)
  float* out = (float*)d_out;                    // (8, 4096, 512) f32

  char* ws = (char*)d_ws;
  unsigned short* qkv_p   = (unsigned short*)ws;                 // 96MB: q|k|v window-major
  unsigned short* xh      = (unsigned short*)(ws + 100663296);   // 32MB: x f16; reused as attn_out
  unsigned short* wqkv_h  = (unsigned short*)(ws + 134217728);   // 1536*512 f16
  unsigned short* wproj_h = (unsigned short*)(ws + 135790592);   // 512*512 f16
  unsigned short* wlep_h  = (unsigned short*)(ws + 136314880);   // 2*9*256 f16

  // casts: x (big) + all weights in one launch
  cvt_f32_f16<<<16384, 256, 0, stream>>>(x, xh, 4194304);
  cvt_weights<<<1029, 256, 0, stream>>>(w_qkv, w_proj, lepe_h, lepe_v,
                                        wqkv_h, wproj_h, wlep_h);

  // qkv = x @ w_qkv^T -> window-major f16 (256^2, BK=32 dbuf, 2 blocks/CU)
  gemm256<1><<<768, 512, 0, stream>>>(
      xh, wqkv_h, qkv_p, nullptr, nullptr, 32768, 1536);

  // stripe attention + LePE -> attn_out token-major (xh dead -> reuse)
  attn_lepe<<<8192, 256, 0, stream>>>(qkv_p, wlep_h, xh);

  // out = attn_out @ w_proj^T + b_proj -> f32
  gemm256<0><<<256, 512, 0, stream>>>(
      xh, wproj_h, nullptr, out, b_proj, 32768, 512);
}

// Round 15
// 183.330 us; speedup vs baseline: 4.2108x; 4.2108x over previous
//
#include <hip/hip_runtime.h>
#include <hip/hip_bf16.h>
#include <stdint.h>

// ---------- types ----------
typedef _Float16 half2v __attribute__((ext_vector_type(2)));
typedef _Float16 half8v __attribute__((ext_vector_type(8)));
typedef uint32_t u32x4  __attribute__((ext_vector_type(4)));
typedef float    f32x4  __attribute__((ext_vector_type(4)));

__device__ __forceinline__ unsigned short f2h(float f) {
  _Float16 h = (_Float16)f;
  return __builtin_bit_cast(unsigned short, h);
}
__device__ __forceinline__ half2v bch2(uint32_t u) {
  return __builtin_bit_cast(half2v, u);
}
__device__ __forceinline__ uint32_t pkrtz_u32(float a, float b) {
  return __builtin_bit_cast(uint32_t, __builtin_amdgcn_cvt_pkrtz(a, b));
}

// Window-major qkv layout (channel 0 of head n, pixel (h,w)).
__device__ __forceinline__ int qkv_idx(int half, int b, int n, int h, int w) {
  int idx = half * 8388608 + (b * 8 + n) * 131072;
  idx += (half == 0) ? ((h >> 3) * 16384 + w * 256 + (h & 7) * 32)
                     : (h * 2048 + w * 32);
  return idx;
}

// async global->LDS, 16 bytes per lane. lbase = wave-uniform base.
#define GLOAD_LDS16(gsrc, lbase)                                          \
  __builtin_amdgcn_global_load_lds(                                       \
      (const __attribute__((address_space(1))) uint32_t*)(gsrc),          \
      (__attribute__((address_space(3))) uint32_t*)(lbase), 16, 0, 0)

// ---------- f32 -> f16 conversion of x (4 elems/thread) ----------
__global__ __launch_bounds__(256) void cvt_f32_f16(const float* __restrict__ in,
                                                   unsigned short* __restrict__ out,
                                                   int n4) {
  int i = blockIdx.x * 256 + threadIdx.x;
  if (i >= n4) return;
  float4 f = reinterpret_cast<const float4*>(in)[i];
  ushort4 u;
  u.x = f2h(f.x); u.y = f2h(f.y); u.z = f2h(f.z); u.w = f2h(f.w);
  reinterpret_cast<ushort4*>(out)[i] = u;
}

// ---------- all weight casts in ONE launch ----------
__global__ __launch_bounds__(256) void cvt_weights(
    const float* __restrict__ wqkv, const float* __restrict__ wproj,
    const float* __restrict__ lh,   const float* __restrict__ lv,
    unsigned short* __restrict__ owqkv, unsigned short* __restrict__ owproj,
    unsigned short* __restrict__ owlep)
{
  int i = blockIdx.x * 256 + threadIdx.x;   // float4 index
  const float* src; unsigned short* dst; int off;
  if      (i < 196608) { src = wqkv;  dst = owqkv;        off = i; }
  else if (i < 262144) { src = wproj; dst = owproj;       off = i - 196608; }
  else if (i < 262720) { src = lh;    dst = owlep;        off = i - 262144; }
  else if (i < 263296) { src = lv;    dst = owlep + 2304; off = i - 262720; }
  else return;
  float4 f = reinterpret_cast<const float4*>(src)[off];
  ushort4 u;
  u.x = f2h(f.x); u.y = f2h(f.y); u.z = f2h(f.z); u.w = f2h(f.w);
  reinterpret_cast<ushort4*>(dst)[off] = u;
}

// ---------- 256^2 f16 GEMM, BK=32 dbuf (64KB LDS -> 2 blocks/CU) ----------
// C[m,n] = sum_k A[m,k]*B[n,k]; 512 thr = 8 waves (2M x 4N), wave tile 128x64,
// MFMA 16x16x32 operand-swapped. R7/R9-PROVEN sync skeleton: stage t+1 ->
// counted vmcnt(4) (never 0 in loop) -> s_barrier -> compute (12 ds_read_b128
// + 32 MFMA) -> s_barrier. LDS caps residency at 2 blocks/CU (cross-block TLP
// hides the vmcnt/barrier waits); 256^2 doubles FLOP per staged byte vs 128^2.
// launch_bounds(512,2): min 2 waves/EU -> VGPR cap 256/lane, NO acc spill
// (R14's (512,4) forced 64 VGPR and spilled acc -> 1.37GB scratch traffic).
// Proven R9 swizzle formulas verbatim (2 lanes/bank = free).
// 1D grid + bijective XCD swizzle, n-fast in XCD chunk.
// MODE 0: f32 out + bias token-major. MODE 1: f16 scatter to qkv windows.
template<int MODE>
__global__ __launch_bounds__(512, 2) void gemm256(
    const unsigned short* __restrict__ A,
    const unsigned short* __restrict__ Bm,
    unsigned short* __restrict__ Cq,
    float* __restrict__ Cf,
    const float* __restrict__ bias,
    int M, int N)
{
  constexpr int K = 512;
  __shared__ unsigned short As[2][256 * 32];   // 2 x 16KB
  __shared__ unsigned short Bs[2][256 * 32];   // 2 x 16KB
  const int tid  = threadIdx.x;
  const int gn   = N >> 8;
  const int cpx  = gridDim.x >> 3;
  const int bid  = blockIdx.x;
  const int wgid = (bid & 7) * cpx + (bid >> 3);   // bijective (grid%8==0)
  const int m0   = (wgid / gn) * 256;
  const int n0   = (wgid % gn) * 256;
  const int wave = tid >> 6, lane = tid & 63;
  const int wr  = wave >> 2;        // 0..1 (128 M-rows)
  const int wcn = wave & 3;         // 0..3 (64 N-cols)
  // staging (R9 formulas): row sr (128/issue), pre-swizzled 16B chunk
  const int sr = tid >> 2;                                // 0..127
  const int sc = ((tid & 3) ^ ((tid >> 3) & 3)) * 8;
  const size_t aBase0 = (size_t)(m0 + sr) * K + sc;
  const size_t aBase1 = (size_t)(m0 + 128 + sr) * K + sc;
  const size_t bBase0 = (size_t)(n0 + sr) * K + sc;
  const size_t bBase1 = (size_t)(n0 + 128 + sr) * K + sc;
  char* ldsA = (char*)(&As[0][0]) + (tid & ~63) * 16;
  char* ldsB = (char*)(&Bs[0][0]) + (tid & ~63) * 16;

#define STAGE(bsel, kofs)                                           \
  do {                                                              \
    GLOAD_LDS16(A  + aBase0 + (kofs), ldsA + (bsel) * 16384);        \
    GLOAD_LDS16(A  + aBase1 + (kofs), ldsA + (bsel) * 16384 + 8192); \
    GLOAD_LDS16(Bm + bBase0 + (kofs), ldsB + (bsel) * 16384);        \
    GLOAD_LDS16(Bm + bBase1 + (kofs), ldsB + (bsel) * 16384 + 8192); \
  } while (0)

  STAGE(0, 0);

  f32x4 acc[8][4];
  const f32x4 zero = {0.f, 0.f, 0.f, 0.f};
  #pragma unroll
  for (int i = 0; i < 8; ++i)
    #pragma unroll
    for (int j = 0; j < 4; ++j) acc[i][j] = zero;

  const int lr   = lane & 15;
  const int slot = (lane >> 4) ^ ((lr >> 1) & 3);   // proven 2-way-free swizzle

  auto compute = [&](const unsigned short* Asb, const unsigned short* Bsb) {
    half8v bf[4];
    #pragma unroll
    for (int j = 0; j < 4; ++j)
      bf[j] = *reinterpret_cast<const half8v*>(Bsb + (wcn * 64 + j * 16 + lr) * 32 + slot * 8);
    half8v af[8];
    #pragma unroll
    for (int i = 0; i < 8; ++i)
      af[i] = *reinterpret_cast<const half8v*>(Asb + (wr * 128 + i * 16 + lr) * 32 + slot * 8);
    __builtin_amdgcn_s_setprio(1);
    #pragma unroll
    for (int i = 0; i < 8; ++i)
      #pragma unroll
      for (int j = 0; j < 4; ++j)
        acc[i][j] = __builtin_amdgcn_mfma_f32_16x16x32_f16(bf[j], af[i], acc[i][j], 0, 0, 0);
    __builtin_amdgcn_s_setprio(0);
  };

  const int nt = K >> 5;   // 16
  for (int t = 0; t < nt - 1; ++t) {
    STAGE((t + 1) & 1, (t + 1) * 32);                // issue next-tile loads
    asm volatile("s_waitcnt vmcnt(4)" ::: "memory"); // tile t landed; t+1 in flight
    __builtin_amdgcn_s_barrier();
    __builtin_amdgcn_sched_barrier(0);
    compute(&As[t & 1][0], &Bs[t & 1][0]);
    __builtin_amdgcn_s_barrier();                    // all done reading buf[t&1]
    __builtin_amdgcn_sched_barrier(0);
  }
  asm volatile("s_waitcnt vmcnt(0)" ::: "memory");
  __builtin_amdgcn_s_barrier();
  __builtin_amdgcn_sched_barrier(0);
  compute(&As[(nt - 1) & 1][0], &Bs[(nt - 1) & 1][0]);
#undef STAGE

  // D layout (operand-swapped): row(n) = (lane>>4)*4 + e, col(m) = lane&15
  const int cr = (lane >> 4) * 4;   // channel offset (4 contiguous)
  const int cc = lane & 15;         // token offset

  if constexpr (MODE == 0) {
    #pragma unroll
    for (int j = 0; j < 4; ++j) {
      const int n = n0 + wcn * 64 + j * 16 + cr;
      const float4 b4 = *reinterpret_cast<const float4*>(bias + n);
      #pragma unroll
      for (int i = 0; i < 8; ++i) {
        const int m = m0 + wr * 128 + i * 16 + cc;
        float4 r;
        r.x = acc[i][j][0] + b4.x;
        r.y = acc[i][j][1] + b4.y;
        r.z = acc[i][j][2] + b4.z;
        r.w = acc[i][j][3] + b4.w;
        *reinterpret_cast<float4*>(Cf + (size_t)m * N + n) = r;
      }
    }
  } else {
    const int mb   = m0 + wr * 128;   // token base (wave-uniform, 128-aligned)
    const int btok = mb >> 12;
    const int hr0  = (mb >> 6) & 63;  // wave spans h-rows hr0, hr0+1
    #pragma unroll
    for (int j = 0; j < 4; ++j) {
      const int nb    = n0 + wcn * 64 + j * 16 + cr;  // 4 contiguous channels
      const int tq    = nb >> 9;                      // 0=q 1=k 2=v
      const int halfc = (nb >> 8) & 1;
      const int nn    = (nb & 255) >> 5;
      const int ch4   = nb & 31;
      const int headbase = tq * 16777216 + halfc * 8388608 +
                           (btok * 8 + nn) * 131072 + ch4;
      #pragma unroll
      for (int i = 0; i < 8; ++i) {
        const int hrow = hr0 + (i >> 2);
        const int wpix = (i & 3) * 16 + cc;
        const int off = halfc ? (hrow * 2048 + wpix * 32)
                              : ((hrow >> 3) * 16384 + wpix * 256 + (hrow & 7) * 32);
        uint2 r;
        r.x = pkrtz_u32(acc[i][j][0], acc[i][j][1]);
        r.y = pkrtz_u32(acc[i][j][2], acc[i][j][3]);
        *reinterpret_cast<uint2*>(Cq + headbase + off) = r;
      }
    }
  }
}

// ---------- stripe attention + LePE, TWO windows per wave ----------
__global__ __launch_bounds__(256) void attn_lepe(
    const unsigned short* __restrict__ qkvp,
    const unsigned short* __restrict__ wlep,
    unsigned short* __restrict__ outp)
{
  const int gw   = (int)((blockIdx.x * 256 + threadIdx.x) >> 6);  // pair index
  const int lane = threadIdx.x & 63;
  const int half = gw >> 14;
  const int id   = gw & 16383;
  const int b    = id >> 11;
  const int n    = (id >> 8) & 7;
  int h0, w0;
  if (half == 0) { h0 = ((id >> 5) & 7) * 8; w0 = (id & 31) * 2; }
  else           { h0 = ((id >> 3) & 31) * 2; w0 = (id & 7) * 8; }
  const int baseA = qkv_idx(half, b, n, h0, w0);
  const int dWin  = (half == 0) ? 256 : 2048;
  const int baseB = baseA + dWin;

  // ---- QK^T for both windows: lane = (qr, kr) ----
  const int qr = lane >> 3, kr = lane & 7;
  const unsigned short* qA = qkvp + baseA + qr * 32;
  const unsigned short* kA = qkvp + 16777216 + baseA + kr * 32;
  float sA = 0.f, sB = 0.f;
  #pragma unroll
  for (int c = 0; c < 4; ++c) {
    const u32x4 qa = *reinterpret_cast<const u32x4*>(qA + c * 8);
    const u32x4 ka = *reinterpret_cast<const u32x4*>(kA + c * 8);
    const u32x4 qb = *reinterpret_cast<const u32x4*>(qA + dWin + c * 8);
    const u32x4 kb = *reinterpret_cast<const u32x4*>(kA + dWin + c * 8);
    #pragma unroll
    for (int e = 0; e < 4; ++e) {
      sA = __builtin_amdgcn_fdot2(bch2(qa[e]), bch2(ka[e]), sA, false);
      sB = __builtin_amdgcn_fdot2(bch2(qb[e]), bch2(kb[e]), sB, false);
    }
  }
  const float scl = 0.17677669529663687f;
  const float pA = __expf(sA * scl);
  const float pB = __expf(sB * scl);
  float denA = pA, denB = pB;
  denA += __shfl_xor(denA, 1); denA += __shfl_xor(denA, 2); denA += __shfl_xor(denA, 4);
  denB += __shfl_xor(denB, 1); denB += __shfl_xor(denB, 2); denB += __shfl_xor(denB, 4);
  const float aAv = pA * __builtin_amdgcn_rcpf(denA);
  const float aBv = pB * __builtin_amdgcn_rcpf(denB);
  const uint32_t adu = pkrtz_u32(aAv, aBv);   // lo = winA, hi = winB

  // ---- PV: lane = (qr2, win, dgrp); 16B vectors over 8 channels ----
  const int dgrp = lane & 3;
  const int win  = (lane >> 2) & 1;
  const int qr2  = lane >> 3;
  const int d0   = dgrp * 8;
  const int mybase = win ? baseB : baseA;
  const unsigned short* vwin = qkvp + 33554432 + mybase;

  half2v o01 = {0,0}, o23 = {0,0}, o45 = {0,0}, o67 = {0,0};
  #pragma unroll
  for (int k = 0; k < 8; ++k) {
    const uint32_t pairw = (uint32_t)__shfl((int)adu, qr2 * 8 + k);
    const half2v ph = bch2(pairw);
    const _Float16 av = win ? ph.y : ph.x;
    const half2v ak2 = {av, av};
    const u32x4 vv = *reinterpret_cast<const u32x4*>(vwin + k * 32 + d0);
    o01 += ak2 * bch2(vv[0]);
    o23 += ak2 * bch2(vv[1]);
    o45 += ak2 * bch2(vv[2]);
    o67 += ak2 * bch2(vv[3]);
  }

  // ---- LePE: depthwise 3x3 on v (zero-pad SAME) at this lane's pixel ----
  const int hq = (half == 0) ? (h0 + qr2) : (h0 + win);
  const int wq = (half == 0) ? (w0 + win) : (w0 + qr2);
  const unsigned short* vplane = qkvp + 33554432;
  const unsigned short* wl = wlep + half * 2304 + n * 32 + d0;
  half2v l01 = {0,0}, l23 = {0,0}, l45 = {0,0}, l67 = {0,0};
  #pragma unroll
  for (int dy = -1; dy <= 1; ++dy) {
    #pragma unroll
    for (int dx = -1; dx <= 1; ++dx) {
      const int hh = hq + dy, ww = wq + dx;
      u32x4 vv = {0u, 0u, 0u, 0u};
      if ((unsigned)hh < 64u && (unsigned)ww < 64u)
        vv = *reinterpret_cast<const u32x4*>(vplane + qkv_idx(half, b, n, hh, ww) + d0);
      const u32x4 wt = *reinterpret_cast<const u32x4*>(wl + ((dy + 1) * 3 + dx + 1) * 256);
      l01 += bch2(wt[0]) * bch2(vv[0]);
      l23 += bch2(wt[1]) * bch2(vv[1]);
      l45 += bch2(wt[2]) * bch2(vv[2]);
      l67 += bch2(wt[3]) * bch2(vv[3]);
    }
  }

  // ---- store token-major for GEMM2 (16B per lane) ----
  const int m = b * 4096 + hq * 64 + wq;
  const int chan0 = half * 256 + n * 32;
  u32x4 r;
  r[0] = __builtin_bit_cast(uint32_t, (half2v)(o01 + l01));
  r[1] = __builtin_bit_cast(uint32_t, (half2v)(o23 + l23));
  r[2] = __builtin_bit_cast(uint32_t, (half2v)(o45 + l45));
  r[3] = __builtin_bit_cast(uint32_t, (half2v)(o67 + l67));
  *reinterpret_cast<u32x4*>(outp + (size_t)m * 512 + chan0 + d0) = r;
}

// ---------- launch ----------
extern "C" void kernel_launch(void* const* d_in, const int* in_sizes, int n_in,
                              void* d_out, int out_size, void* d_ws, size_t ws_size,
                              hipStream_t stream) {
  const float* x      = (const float*)d_in[0];   // (8, 4096, 512)
  const float* w_qkv  = (const float*)d_in[1];   // (1536, 512)
  const float* w_proj = (const float*)d_in[2];   // (512, 512)
  const float* b_proj = (const float*)d_in[3];   // (512,)
  const float* lepe_h = (const float*)d_in[4];   // (3,3,1,256)
  const float* lepe_v = (const float*)d_in[5];   // (3,3,1,256)
  float* out = (float*)d_out;                    // (8, 4096, 512) f32

  char* ws = (char*)d_ws;
  unsigned short* qkv_p   = (unsigned short*)ws;                 // 96MB: q|k|v window-major
  unsigned short* xh      = (unsigned short*)(ws + 100663296);   // 32MB: x f16; reused as attn_out
  unsigned short* wqkv_h  = (unsigned short*)(ws + 134217728);   // 1536*512 f16
  unsigned short* wproj_h = (unsigned short*)(ws + 135790592);   // 512*512 f16
  unsigned short* wlep_h  = (unsigned short*)(ws + 136314880);   // 2*9*256 f16

  // casts: x (big) + all weights in one launch
  cvt_f32_f16<<<16384, 256, 0, stream>>>(x, xh, 4194304);
  cvt_weights<<<1029, 256, 0, stream>>>(w_qkv, w_proj, lepe_h, lepe_v,
                                        wqkv_h, wproj_h, wlep_h);

  // qkv = x @ w_qkv^T -> window-major f16 (256^2, BK=32 dbuf, 2 blocks/CU)
  gemm256<1><<<768, 512, 0, stream>>>(
      xh, wqkv_h, qkv_p, nullptr, nullptr, 32768, 1536);

  // stripe attention + LePE -> attn_out token-major (xh dead -> reuse)
  attn_lepe<<<8192, 256, 0, stream>>>(qkv_p, wlep_h, xh);

  // out = attn_out @ w_proj^T + b_proj -> f32
  gemm256<0><<<256, 512, 0, stream>>>(
      xh, wproj_h, nullptr, out, b_proj, 32768, 512);
}

// Round 16
// 173.393 us; speedup vs baseline: 4.4521x; 1.0573x over previous
//
#include <hip/hip_runtime.h>
#include <hip/hip_bf16.h>
#include <stdint.h>

// ---------- types ----------
typedef _Float16 half2v __attribute__((ext_vector_type(2)));
typedef _Float16 half8v __attribute__((ext_vector_type(8)));
typedef uint32_t u32x4  __attribute__((ext_vector_type(4)));
typedef float    f32x4  __attribute__((ext_vector_type(4)));

__device__ __forceinline__ unsigned short f2h(float f) {
  _Float16 h = (_Float16)f;
  return __builtin_bit_cast(unsigned short, h);
}
__device__ __forceinline__ half2v bch2(uint32_t u) {
  return __builtin_bit_cast(half2v, u);
}
__device__ __forceinline__ uint32_t pkrtz_u32(float a, float b) {
  return __builtin_bit_cast(uint32_t, __builtin_amdgcn_cvt_pkrtz(a, b));
}

// Window-major qkv layout (channel 0 of head n, pixel (h,w)).
__device__ __forceinline__ int qkv_idx(int half, int b, int n, int h, int w) {
  int idx = half * 8388608 + (b * 8 + n) * 131072;
  idx += (half == 0) ? ((h >> 3) * 16384 + w * 256 + (h & 7) * 32)
                     : (h * 2048 + w * 32);
  return idx;
}

// async global->LDS, 16 bytes per lane. lbase = wave-uniform base.
#define GLOAD_LDS16(gsrc, lbase)                                          \
  __builtin_amdgcn_global_load_lds(                                       \
      (const __attribute__((address_space(1))) uint32_t*)(gsrc),          \
      (__attribute__((address_space(3))) uint32_t*)(lbase), 16, 0, 0)

// ---------- f32 -> f16 conversion of x (4 elems/thread) ----------
__global__ __launch_bounds__(256) void cvt_f32_f16(const float* __restrict__ in,
                                                   unsigned short* __restrict__ out,
                                                   int n4) {
  int i = blockIdx.x * 256 + threadIdx.x;
  if (i >= n4) return;
  float4 f = reinterpret_cast<const float4*>(in)[i];
  ushort4 u;
  u.x = f2h(f.x); u.y = f2h(f.y); u.z = f2h(f.z); u.w = f2h(f.w);
  reinterpret_cast<ushort4*>(out)[i] = u;
}

// ---------- all weight casts in ONE launch ----------
__global__ __launch_bounds__(256) void cvt_weights(
    const float* __restrict__ wqkv, const float* __restrict__ wproj,
    const float* __restrict__ lh,   const float* __restrict__ lv,
    unsigned short* __restrict__ owqkv, unsigned short* __restrict__ owproj,
    unsigned short* __restrict__ owlep)
{
  int i = blockIdx.x * 256 + threadIdx.x;   // float4 index
  const float* src; unsigned short* dst; int off;
  if      (i < 196608) { src = wqkv;  dst = owqkv;        off = i; }
  else if (i < 262144) { src = wproj; dst = owproj;       off = i - 196608; }
  else if (i < 262720) { src = lh;    dst = owlep;        off = i - 262144; }
  else if (i < 263296) { src = lv;    dst = owlep + 2304; off = i - 262720; }
  else return;
  float4 f = reinterpret_cast<const float4*>(src)[off];
  ushort4 u;
  u.x = f2h(f.x); u.y = f2h(f.y); u.z = f2h(f.z); u.w = f2h(f.w);
  reinterpret_cast<ushort4*>(dst)[off] = u;
}

// ---------- GEMM1: 8-phase 256^2 f16 (R13-proven, best measured) ----------
// 512 thr = 8 waves (2M x 4N), wave tile 128x64, MFMA 16x16x32 operand-swap.
// LDS 128KB: 2 K-tile buffers (BK=64) x (A 32KB + B 32KB). 8 phases / 2
// K-tiles; stage slots p1/p4/p5/p8 with counted vmcnt(4) at p4/p8 only.
// Chunk-XOR swizzle (pre-swizzled source; read slot ck0 = kg^(lr&7)).
// MODE 1: f16 scatter to window-major qkv regions.
template<int MODE>
__global__ __launch_bounds__(512, 2) void gemm8(
    const unsigned short* __restrict__ A,
    const unsigned short* __restrict__ Bm,
    unsigned short* __restrict__ Cq,
    float* __restrict__ Cf,
    const float* __restrict__ bias,
    int M, int N)
{
  constexpr int K = 512;
  constexpr int NIT = 4;                    // K / 128
  __shared__ unsigned short As[2][256 * 64];   // 2 x 32KB
  __shared__ unsigned short Bs[2][256 * 64];   // 2 x 32KB
  const int tid  = threadIdx.x;
  const int gn   = N >> 8;
  const int cpx  = gridDim.x >> 3;
  const int bid  = blockIdx.x;
  const int wgid = (bid & 7) * cpx + (bid >> 3);   // bijective (grid%8==0)
  const int m0   = (wgid / gn) * 256;
  const int n0   = (wgid % gn) * 256;
  const int wave = tid >> 6, lane = tid & 63;
  const int wr  = wave >> 2;        // 0..1 (128 M-rows)
  const int wcn = wave & 3;         // 0..3 (64 N-cols)

  const int srow = tid >> 3;
  const int schk = ((tid & 7) ^ (srow & 7)) * 8;
  const size_t aSrc = (size_t)(m0 + srow) * K + schk;
  const size_t bSrc = (size_t)(n0 + srow) * K + schk;
  char* ldsA = (char*)(&As[0][0]) + (tid & ~63) * 16;
  char* ldsB = (char*)(&Bs[0][0]) + (tid & ~63) * 16;

#define STAGE_A8(b, kt)                                                     \
  do {                                                                      \
    GLOAD_LDS16(A + aSrc + (size_t)(kt) * 64,             ldsA + (b) * 32768);         \
    GLOAD_LDS16(A + aSrc + (size_t)64 * K + (kt) * 64,    ldsA + (b) * 32768 + 8192);  \
    GLOAD_LDS16(A + aSrc + (size_t)128 * K + (kt) * 64,   ldsA + (b) * 32768 + 16384); \
    GLOAD_LDS16(A + aSrc + (size_t)192 * K + (kt) * 64,   ldsA + (b) * 32768 + 24576); \
  } while (0)
#define STAGE_B8(b, kt)                                                     \
  do {                                                                      \
    GLOAD_LDS16(Bm + bSrc + (size_t)(kt) * 64,            ldsB + (b) * 32768);         \
    GLOAD_LDS16(Bm + bSrc + (size_t)64 * K + (kt) * 64,   ldsB + (b) * 32768 + 8192);  \
    GLOAD_LDS16(Bm + bSrc + (size_t)128 * K + (kt) * 64,  ldsB + (b) * 32768 + 16384); \
    GLOAD_LDS16(Bm + bSrc + (size_t)192 * K + (kt) * 64,  ldsB + (b) * 32768 + 24576); \
  } while (0)
#define BARS                                                                \
  __builtin_amdgcn_s_barrier();                                             \
  __builtin_amdgcn_sched_barrier(0)

  STAGE_A8(0, 0);
  STAGE_B8(0, 0);
  STAGE_B8(1, 1);

  f32x4 acc[8][4];
  const f32x4 zero = {0.f, 0.f, 0.f, 0.f};
  #pragma unroll
  for (int i = 0; i < 8; ++i)
    #pragma unroll
    for (int j = 0; j < 4; ++j) acc[i][j] = zero;

  const int lr  = lane & 15;
  const int kg  = lane >> 4;
  const int ck0 = kg ^ (lr & 7);            // k-step0 slot; k-step1 = ck0^4

  asm volatile("s_waitcnt vmcnt(4)" ::: "memory");
  BARS;

#define LD_AF(buf, mg, ks)                                                  \
  do {                                                                      \
    const unsigned short* ap = &As[buf][0] +                                \
        (wr * 128 + (mg) * 64 + lr) * 64 + (((ks) ? (ck0 ^ 4) : ck0)) * 8;  \
    af[0] = *(const half8v*)(ap);                                           \
    af[1] = *(const half8v*)(ap + 1024);                                    \
    af[2] = *(const half8v*)(ap + 2048);                                    \
    af[3] = *(const half8v*)(ap + 3072);                                    \
  } while (0)
#define LD_BF(buf, ks)                                                      \
  do {                                                                      \
    const unsigned short* bp = &Bs[buf][0] +                                \
        (wcn * 64 + lr) * 64 + (((ks) ? (ck0 ^ 4) : ck0)) * 8;              \
    bf[0] = *(const half8v*)(bp);                                           \
    bf[1] = *(const half8v*)(bp + 1024);                                    \
    bf[2] = *(const half8v*)(bp + 2048);                                    \
    bf[3] = *(const half8v*)(bp + 3072);                                    \
  } while (0)
#define MROW(mg, i)                                                         \
  acc[(mg)*4+(i)][0] = __builtin_amdgcn_mfma_f32_16x16x32_f16(bf[0], af[i], acc[(mg)*4+(i)][0], 0, 0, 0); \
  acc[(mg)*4+(i)][1] = __builtin_amdgcn_mfma_f32_16x16x32_f16(bf[1], af[i], acc[(mg)*4+(i)][1], 0, 0, 0); \
  acc[(mg)*4+(i)][2] = __builtin_amdgcn_mfma_f32_16x16x32_f16(bf[2], af[i], acc[(mg)*4+(i)][2], 0, 0, 0); \
  acc[(mg)*4+(i)][3] = __builtin_amdgcn_mfma_f32_16x16x32_f16(bf[3], af[i], acc[(mg)*4+(i)][3], 0, 0, 0);
#define MFMA16(mg)                                                          \
  do {                                                                      \
    __builtin_amdgcn_s_setprio(1);                                          \
    MROW(mg, 0); MROW(mg, 1); MROW(mg, 2); MROW(mg, 3);                     \
    __builtin_amdgcn_s_setprio(0);                                          \
  } while (0)

  for (int it2 = 0; it2 < NIT; ++it2) {
    const bool more = (it2 + 1 < NIT);
    const int keven = 2 * it2;
    half8v af[4], bf[4];
    // p1
    LD_BF(0, 0); LD_AF(0, 0, 0);
    STAGE_A8(1, keven + 1);
    BARS;
    MFMA16(0);
    BARS;
    // p2
    LD_AF(0, 1, 0);
    BARS;
    MFMA16(1);
    BARS;
    // p3
    LD_BF(0, 1); LD_AF(0, 0, 1);
    BARS;
    MFMA16(0);
    BARS;
    // p4
    LD_AF(0, 1, 1);
    if (more) {
      STAGE_B8(0, keven + 2);
      asm volatile("s_waitcnt vmcnt(4)" ::: "memory");
    } else {
      asm volatile("s_waitcnt vmcnt(0)" ::: "memory");
    }
    BARS;
    MFMA16(1);
    BARS;
    // p5
    LD_BF(1, 0); LD_AF(1, 0, 0);
    if (more) STAGE_A8(0, keven + 2);
    BARS;
    MFMA16(0);
    BARS;
    // p6
    LD_AF(1, 1, 0);
    BARS;
    MFMA16(1);
    BARS;
    // p7
    LD_BF(1, 1); LD_AF(1, 0, 1);
    BARS;
    MFMA16(0);
    BARS;
    // p8
    LD_AF(1, 1, 1);
    if (more) {
      STAGE_B8(1, keven + 3);
      asm volatile("s_waitcnt vmcnt(4)" ::: "memory");
    }
    BARS;
    MFMA16(1);
    BARS;
  }
#undef STAGE_A8
#undef STAGE_B8
#undef LD_AF
#undef LD_BF
#undef MROW
#undef MFMA16
#undef BARS

  const int cr = (lane >> 4) * 4;   // channel offset (4 contiguous)
  const int cc = lane & 15;         // token offset

  if constexpr (MODE == 0) {
    #pragma unroll
    for (int j = 0; j < 4; ++j) {
      const int n = n0 + wcn * 64 + j * 16 + cr;
      const float4 b4 = *reinterpret_cast<const float4*>(bias + n);
      #pragma unroll
      for (int i = 0; i < 8; ++i) {
        const int m = m0 + wr * 128 + i * 16 + cc;
        float4 r;
        r.x = acc[i][j][0] + b4.x;
        r.y = acc[i][j][1] + b4.y;
        r.z = acc[i][j][2] + b4.z;
        r.w = acc[i][j][3] + b4.w;
        *reinterpret_cast<float4*>(Cf + (size_t)m * N + n) = r;
      }
    }
  } else {
    const int mb   = m0 + wr * 128;
    const int btok = mb >> 12;
    const int hr0  = (mb >> 6) & 63;
    #pragma unroll
    for (int j = 0; j < 4; ++j) {
      const int nb    = n0 + wcn * 64 + j * 16 + cr;
      const int tq    = nb >> 9;
      const int halfc = (nb >> 8) & 1;
      const int nn    = (nb & 255) >> 5;
      const int ch4   = nb & 31;
      const int headbase = tq * 16777216 + halfc * 8388608 +
                           (btok * 8 + nn) * 131072 + ch4;
      #pragma unroll
      for (int i = 0; i < 8; ++i) {
        const int hrow = hr0 + (i >> 2);
        const int wpix = (i & 3) * 16 + cc;
        const int off = halfc ? (hrow * 2048 + wpix * 32)
                              : ((hrow >> 3) * 16384 + wpix * 256 + (hrow & 7) * 32);
        uint2 r;
        r.x = pkrtz_u32(acc[i][j][0], acc[i][j][1]);
        r.y = pkrtz_u32(acc[i][j][2], acc[i][j][3]);
        *reinterpret_cast<uint2*>(Cq + headbase + off) = r;
      }
    }
  }
}

// ---------- GEMM2: out = attn_out(f16) @ w_proj(f16)^T + bias -> f32 ----------
// R9-proven 128x128 2-phase, gload_lds, counted vmcnt(4); grid 1024 = 4/CU TLP.
__global__ __launch_bounds__(256) void gemm_proj(
    const unsigned short* __restrict__ A,
    const unsigned short* __restrict__ B,
    float* __restrict__ Cf,
    const float* __restrict__ bias)
{
  constexpr int K = 512, N = 512;
  __shared__ unsigned short As[2][128 * 32];
  __shared__ unsigned short Bs[2][128 * 32];
  const int tid  = threadIdx.x;
  const int gn   = N >> 7;                 // 4
  const int cpx  = gridDim.x >> 3;
  const int bid  = blockIdx.x;
  const int wgid = (bid & 7) * cpx + (bid >> 3);
  const int m0   = (wgid / gn) * 128;
  const int n0   = (wgid % gn) * 128;
  const int wave = tid >> 6, lane = tid & 63;
  const int wr = wave >> 1, wc = wave & 1;
  const int sr = tid >> 2;
  const int sc = ((tid & 3) ^ ((tid >> 3) & 3)) * 8;
  const size_t aBase0 = (size_t)(m0 + sr) * K + sc;
  const size_t aBase1 = (size_t)(m0 + 64 + sr) * K + sc;
  const size_t bBase0 = (size_t)(n0 + sr) * K + sc;
  const size_t bBase1 = (size_t)(n0 + 64 + sr) * K + sc;
  char* ldsA = (char*)(&As[0][0]) + (tid & ~63) * 16;
  char* ldsB = (char*)(&Bs[0][0]) + (tid & ~63) * 16;

#define STAGE_P(bsel, kofs)                                        \
  do {                                                             \
    GLOAD_LDS16(A + aBase0 + (kofs), ldsA + (bsel) * 8192);        \
    GLOAD_LDS16(A + aBase1 + (kofs), ldsA + (bsel) * 8192 + 4096); \
    GLOAD_LDS16(B + bBase0 + (kofs), ldsB + (bsel) * 8192);        \
    GLOAD_LDS16(B + bBase1 + (kofs), ldsB + (bsel) * 8192 + 4096); \
  } while (0)

  STAGE_P(0, 0);

  f32x4 acc[4][4];
  const f32x4 zero = {0.f, 0.f, 0.f, 0.f};
  #pragma unroll
  for (int i = 0; i < 4; ++i)
    #pragma unroll
    for (int j = 0; j < 4; ++j) acc[i][j] = zero;

  const int lr   = lane & 15;
  const int slot = (lane >> 4) ^ ((lr >> 1) & 3);

  auto compute = [&](const unsigned short* Asb, const unsigned short* Bsb) {
    half8v af[4], bfr[4];
    #pragma unroll
    for (int i = 0; i < 4; ++i)
      af[i] = *reinterpret_cast<const half8v*>(Asb + (wr * 64 + i * 16 + lr) * 32 + slot * 8);
    #pragma unroll
    for (int j = 0; j < 4; ++j)
      bfr[j] = *reinterpret_cast<const half8v*>(Bsb + (wc * 64 + j * 16 + lr) * 32 + slot * 8);
    __builtin_amdgcn_s_setprio(1);
    #pragma unroll
    for (int i = 0; i < 4; ++i)
      #pragma unroll
      for (int j = 0; j < 4; ++j)
        acc[i][j] = __builtin_amdgcn_mfma_f32_16x16x32_f16(bfr[j], af[i], acc[i][j], 0, 0, 0);
    __builtin_amdgcn_s_setprio(0);
  };

  const int nt = K >> 5;
  for (int t = 0; t < nt - 1; ++t) {
    STAGE_P((t + 1) & 1, (t + 1) * 32);
    asm volatile("s_waitcnt vmcnt(4)" ::: "memory");
    __builtin_amdgcn_s_barrier();
    __builtin_amdgcn_sched_barrier(0);
    compute(&As[t & 1][0], &Bs[t & 1][0]);
    __builtin_amdgcn_s_barrier();
    __builtin_amdgcn_sched_barrier(0);
  }
  asm volatile("s_waitcnt vmcnt(0)" ::: "memory");
  __builtin_amdgcn_s_barrier();
  __builtin_amdgcn_sched_barrier(0);
  compute(&As[(nt - 1) & 1][0], &Bs[(nt - 1) & 1][0]);
#undef STAGE_P

  const int cr = (lane >> 4) * 4;
  const int cc = lane & 15;
  #pragma unroll
  for (int j = 0; j < 4; ++j) {
    const int n = n0 + wc * 64 + j * 16 + cr;
    const float4 b4 = *reinterpret_cast<const float4*>(bias + n);
    #pragma unroll
    for (int i = 0; i < 4; ++i) {
      const int m = m0 + wr * 64 + i * 16 + cc;
      float4 r;
      r.x = acc[i][j][0] + b4.x;
      r.y = acc[i][j][1] + b4.y;
      r.z = acc[i][j][2] + b4.z;
      r.w = acc[i][j][3] + b4.w;
      *reinterpret_cast<float4*>(Cf + (size_t)m * N + n) = r;
    }
  }
}

// ---------- stripe attention + LePE, TWO windows per wave ----------
__global__ __launch_bounds__(256) void attn_lepe(
    const unsigned short* __restrict__ qkvp,
    const unsigned short* __restrict__ wlep,
    unsigned short* __restrict__ outp)
{
  const int gw   = (int)((blockIdx.x * 256 + threadIdx.x) >> 6);  // pair index
  const int lane = threadIdx.x & 63;
  const int half = gw >> 14;
  const int id   = gw & 16383;
  const int b    = id >> 11;
  const int n    = (id >> 8) & 7;
  int h0, w0;
  if (half == 0) { h0 = ((id >> 5) & 7) * 8; w0 = (id & 31) * 2; }
  else           { h0 = ((id >> 3) & 31) * 2; w0 = (id & 7) * 8; }
  const int baseA = qkv_idx(half, b, n, h0, w0);
  const int dWin  = (half == 0) ? 256 : 2048;
  const int baseB = baseA + dWin;

  // ---- QK^T for both windows: lane = (qr, kr) ----
  const int qr = lane >> 3, kr = lane & 7;
  const unsigned short* qA = qkvp + baseA + qr * 32;
  const unsigned short* kA = qkvp + 16777216 + baseA + kr * 32;
  float sA = 0.f, sB = 0.f;
  #pragma unroll
  for (int c = 0; c < 4; ++c) {
    const u32x4 qa = *reinterpret_cast<const u32x4*>(qA + c * 8);
    const u32x4 ka = *reinterpret_cast<const u32x4*>(kA + c * 8);
    const u32x4 qb = *reinterpret_cast<const u32x4*>(qA + dWin + c * 8);
    const u32x4 kb = *reinterpret_cast<const u32x4*>(kA + dWin + c * 8);
    #pragma unroll
    for (int e = 0; e < 4; ++e) {
      sA = __builtin_amdgcn_fdot2(bch2(qa[e]), bch2(ka[e]), sA, false);
      sB = __builtin_amdgcn_fdot2(bch2(qb[e]), bch2(kb[e]), sB, false);
    }
  }
  const float scl = 0.17677669529663687f;
  const float pA = __expf(sA * scl);
  const float pB = __expf(sB * scl);
  float denA = pA, denB = pB;
  denA += __shfl_xor(denA, 1); denA += __shfl_xor(denA, 2); denA += __shfl_xor(denA, 4);
  denB += __shfl_xor(denB, 1); denB += __shfl_xor(denB, 2); denB += __shfl_xor(denB, 4);
  const float aAv = pA * __builtin_amdgcn_rcpf(denA);
  const float aBv = pB * __builtin_amdgcn_rcpf(denB);
  const uint32_t adu = pkrtz_u32(aAv, aBv);   // lo = winA, hi = winB

  // ---- PV: lane = (qr2, win, dgrp); 16B vectors over 8 channels ----
  const int dgrp = lane & 3;
  const int win  = (lane >> 2) & 1;
  const int qr2  = lane >> 3;
  const int d0   = dgrp * 8;
  const int mybase = win ? baseB : baseA;
  const unsigned short* vwin = qkvp + 33554432 + mybase;

  half2v o01 = {0,0}, o23 = {0,0}, o45 = {0,0}, o67 = {0,0};
  #pragma unroll
  for (int k = 0; k < 8; ++k) {
    const uint32_t pairw = (uint32_t)__shfl((int)adu, qr2 * 8 + k);
    const half2v ph = bch2(pairw);
    const _Float16 av = win ? ph.y : ph.x;
    const half2v ak2 = {av, av};
    const u32x4 vv = *reinterpret_cast<const u32x4*>(vwin + k * 32 + d0);
    o01 += ak2 * bch2(vv[0]);
    o23 += ak2 * bch2(vv[1]);
    o45 += ak2 * bch2(vv[2]);
    o67 += ak2 * bch2(vv[3]);
  }

  // ---- LePE: depthwise 3x3 on v (zero-pad SAME) at this lane's pixel ----
  const int hq = (half == 0) ? (h0 + qr2) : (h0 + win);
  const int wq = (half == 0) ? (w0 + win) : (w0 + qr2);
  const unsigned short* vplane = qkvp + 33554432;
  const unsigned short* wl = wlep + half * 2304 + n * 32 + d0;
  half2v l01 = {0,0}, l23 = {0,0}, l45 = {0,0}, l67 = {0,0};
  #pragma unroll
  for (int dy = -1; dy <= 1; ++dy) {
    #pragma unroll
    for (int dx = -1; dx <= 1; ++dx) {
      const int hh = hq + dy, ww = wq + dx;
      u32x4 vv = {0u, 0u, 0u, 0u};
      if ((unsigned)hh < 64u && (unsigned)ww < 64u)
        vv = *reinterpret_cast<const u32x4*>(vplane + qkv_idx(half, b, n, hh, ww) + d0);
      const u32x4 wt = *reinterpret_cast<const u32x4*>(wl + ((dy + 1) * 3 + dx + 1) * 256);
      l01 += bch2(wt[0]) * bch2(vv[0]);
      l23 += bch2(wt[1]) * bch2(vv[1]);
      l45 += bch2(wt[2]) * bch2(vv[2]);
      l67 += bch2(wt[3]) * bch2(vv[3]);
    }
  }

  // ---- store token-major for GEMM2 (16B per lane) ----
  const int m = b * 4096 + hq * 64 + wq;
  const int chan0 = half * 256 + n * 32;
  u32x4 r;
  r[0] = __builtin_bit_cast(uint32_t, (half2v)(o01 + l01));
  r[1] = __builtin_bit_cast(uint32_t, (half2v)(o23 + l23));
  r[2] = __builtin_bit_cast(uint32_t, (half2v)(o45 + l45));
  r[3] = __builtin_bit_cast(uint32_t, (half2v)(o67 + l67));
  *reinterpret_cast<u32x4*>(outp + (size_t)m * 512 + chan0 + d0) = r;
}

// ---------- launch ----------
extern "C" void kernel_launch(void* const* d_in, const int* in_sizes, int n_in,
                              void* d_out, int out_size, void* d_ws, size_t ws_size,
                              hipStream_t stream) {
  const float* x      = (const float*)d_in[0];   // (8, 4096, 512)
  const float* w_qkv  = (const float*)d_in[1];   // (1536, 512)
  const float* w_proj = (const float*)d_in[2];   // (512, 512)
  const float* b_proj = (const float*)d_in[3];   // (512,)
  const float* lepe_h = (const float*)d_in[4];   // (3,3,1,256)
  const float* lepe_v = (const float*)d_in[5];   // (3,3,1,256)
  float* out = (float*)d_out;                    // (8, 4096, 512) f32

  char* ws = (char*)d_ws;
  unsigned short* qkv_p   = (unsigned short*)ws;                 // 96MB: q|k|v window-major
  unsigned short* xh      = (unsigned short*)(ws + 100663296);   // 32MB: x f16; reused as attn_out
  unsigned short* wqkv_h  = (unsigned short*)(ws + 134217728);   // 1536*512 f16
  unsigned short* wproj_h = (unsigned short*)(ws + 135790592);   // 512*512 f16
  unsigned short* wlep_h  = (unsigned short*)(ws + 136314880);   // 2*9*256 f16

  // casts: x (big) + all weights in one launch
  cvt_f32_f16<<<16384, 256, 0, stream>>>(x, xh, 4194304);
  cvt_weights<<<1029, 256, 0, stream>>>(w_qkv, w_proj, lepe_h, lepe_v,
                                        wqkv_h, wproj_h, wlep_h);

  // qkv = x @ w_qkv^T -> window-major f16 (8-phase 256^2; grid 768)
  gemm8<1><<<768, 512, 0, stream>>>(
      xh, wqkv_h, qkv_p, nullptr, nullptr, 32768, 1536);

  // stripe attention + LePE -> attn_out token-major (xh dead -> reuse)
  attn_lepe<<<8192, 256, 0, stream>>>(qkv_p, wlep_h, xh);

  // out = attn_out @ w_proj^T + b_proj -> f32 (128^2 2-phase; grid 1024 = 4/CU)
  gemm_proj<<<1024, 256, 0, stream>>>(xh, wproj_h, out, b_proj);
}

// Round 17
// 172.534 us; speedup vs baseline: 4.4743x; 1.0050x over previous
//
#include <hip/hip_runtime.h>
#include <hip/hip_bf16.h>
#include <stdint.h>

// ---------- types ----------
typedef _Float16 half2v __attribute__((ext_vector_type(2)));
typedef _Float16 half8v __attribute__((ext_vector_type(8)));
typedef uint32_t u32x4  __attribute__((ext_vector_type(4)));
typedef float    f32x4  __attribute__((ext_vector_type(4)));

__device__ __forceinline__ unsigned short f2h(float f) {
  _Float16 h = (_Float16)f;
  return __builtin_bit_cast(unsigned short, h);
}
__device__ __forceinline__ half2v bch2(uint32_t u) {
  return __builtin_bit_cast(half2v, u);
}
__device__ __forceinline__ uint32_t pkrtz_u32(float a, float b) {
  return __builtin_bit_cast(uint32_t, __builtin_amdgcn_cvt_pkrtz(a, b));
}

// Window-major qkv layout (channel 0 of head n, pixel (h,w)).
__device__ __forceinline__ int qkv_idx(int half, int b, int n, int h, int w) {
  int idx = half * 8388608 + (b * 8 + n) * 131072;
  idx += (half == 0) ? ((h >> 3) * 16384 + w * 256 + (h & 7) * 32)
                     : (h * 2048 + w * 32);
  return idx;
}

// async global->LDS, 16 bytes per lane. lbase = wave-uniform base.
#define GLOAD_LDS16(gsrc, lbase)                                          \
  __builtin_amdgcn_global_load_lds(                                       \
      (const __attribute__((address_space(1))) uint32_t*)(gsrc),          \
      (__attribute__((address_space(3))) uint32_t*)(lbase), 16, 0, 0)

// ---------- ONE cast kernel: x (f32->f16) + all weights ----------
__global__ __launch_bounds__(256) void cvt_all(
    const float* __restrict__ x,
    const float* __restrict__ wqkv, const float* __restrict__ wproj,
    const float* __restrict__ lh,   const float* __restrict__ lv,
    unsigned short* __restrict__ ox,
    unsigned short* __restrict__ owqkv, unsigned short* __restrict__ owproj,
    unsigned short* __restrict__ owlep)
{
  int i = blockIdx.x * 256 + threadIdx.x;   // float4 index
  const float* src; unsigned short* dst; int off;
  if (i < 4194304)      { src = x;     dst = ox;           off = i; }
  else if ((i -= 4194304) < 196608) { src = wqkv;  dst = owqkv;  off = i; }
  else if ((i -= 196608) < 65536)   { src = wproj; dst = owproj; off = i; }
  else if ((i -= 65536) < 576)      { src = lh;    dst = owlep;  off = i; }
  else if ((i -= 576) < 576)        { src = lv;    dst = owlep + 2304; off = i; }
  else return;
  float4 f = reinterpret_cast<const float4*>(src)[off];
  ushort4 u;
  u.x = f2h(f.x); u.y = f2h(f.y); u.z = f2h(f.z); u.w = f2h(f.w);
  reinterpret_cast<ushort4*>(dst)[off] = u;
}

// ---------- GEMM1: 8-phase 256^2 f16 (R13 skeleton, 2-loads/phase spread) ----
// 512 thr = 8 waves (2M x 4N), wave tile 128x64, MFMA 16x16x32 operand-swap.
// LDS 128KB: 2 K-tile buffers (BK=64) x (A 32KB + B 32KB).
// Stage spread (m201 discipline, legality = R13 slots or later within the
// same dead-region): p1/p2 = 2xA-odd; p4 = 2xB-even + vmcnt(2); p5 = 2xB-even;
// p6/p7 = 2xA-even; p8 = 4xB-odd + vmcnt(4).
//   p4 vmcnt(2): outstanding = B-odd-prev(4)+A-odd(4)+B-even(2) -> drain to 2
//   = A-odd & B-odd landed before buf1 reads (p5-p8).
//   p8 vmcnt(4): outstanding = B-even(4)+A-even(4)+B-odd(4) -> drain to 4
//   = buf0's tiles landed before next-iter p1-p4 reads.
// Chunk-XOR swizzle (pre-swizzled source; read slot ck0 = kg^(lr&7)).
template<int MODE>
__global__ __launch_bounds__(512, 2) void gemm8(
    const unsigned short* __restrict__ A,
    const unsigned short* __restrict__ Bm,
    unsigned short* __restrict__ Cq,
    float* __restrict__ Cf,
    const float* __restrict__ bias,
    int M, int N)
{
  constexpr int K = 512;
  constexpr int NIT = 4;                    // K / 128
  __shared__ unsigned short As[2][256 * 64];   // 2 x 32KB
  __shared__ unsigned short Bs[2][256 * 64];   // 2 x 32KB
  const int tid  = threadIdx.x;
  const int gn   = N >> 8;
  const int cpx  = gridDim.x >> 3;
  const int bid  = blockIdx.x;
  const int wgid = (bid & 7) * cpx + (bid >> 3);   // bijective (grid%8==0)
  const int m0   = (wgid / gn) * 256;
  const int n0   = (wgid % gn) * 256;
  const int wave = tid >> 6, lane = tid & 63;
  const int wr  = wave >> 2;        // 0..1 (128 M-rows)
  const int wcn = wave & 3;         // 0..3 (64 N-cols)

  const int srow = tid >> 3;
  const int schk = ((tid & 7) ^ (srow & 7)) * 8;
  const size_t aSrc = (size_t)(m0 + srow) * K + schk;
  const size_t bSrc = (size_t)(n0 + srow) * K + schk;
  char* ldsA = (char*)(&As[0][0]) + (tid & ~63) * 16;
  char* ldsB = (char*)(&Bs[0][0]) + (tid & ~63) * 16;

// stage unit u (rows u*64..u*64+63) of A/B K-tile kt into buffer b
#define SA_U(b, kt, u)                                                      \
  GLOAD_LDS16(A + aSrc + (size_t)(u) * 64 * K + (size_t)(kt) * 64,          \
              ldsA + (b) * 32768 + (u) * 8192)
#define SB_U(b, kt, u)                                                      \
  GLOAD_LDS16(Bm + bSrc + (size_t)(u) * 64 * K + (size_t)(kt) * 64,         \
              ldsB + (b) * 32768 + (u) * 8192)
#define BARS                                                                \
  __builtin_amdgcn_s_barrier();                                             \
  __builtin_amdgcn_sched_barrier(0)

  // prologue: tile0 (buf0) full + tile1 B (buf1) in flight
  SA_U(0, 0, 0); SA_U(0, 0, 1); SA_U(0, 0, 2); SA_U(0, 0, 3);
  SB_U(0, 0, 0); SB_U(0, 0, 1); SB_U(0, 0, 2); SB_U(0, 0, 3);
  SB_U(1, 1, 0); SB_U(1, 1, 1); SB_U(1, 1, 2); SB_U(1, 1, 3);

  f32x4 acc[8][4];
  const f32x4 zero = {0.f, 0.f, 0.f, 0.f};
  #pragma unroll
  for (int i = 0; i < 8; ++i)
    #pragma unroll
    for (int j = 0; j < 4; ++j) acc[i][j] = zero;

  const int lr  = lane & 15;
  const int kg  = lane >> 4;
  const int ck0 = kg ^ (lr & 7);            // k-step0 slot; k-step1 = ck0^4

  asm volatile("s_waitcnt vmcnt(4)" ::: "memory");
  BARS;

#define LD_AF(buf, mg, ks)                                                  \
  do {                                                                      \
    const unsigned short* ap = &As[buf][0] +                                \
        (wr * 128 + (mg) * 64 + lr) * 64 + (((ks) ? (ck0 ^ 4) : ck0)) * 8;  \
    af[0] = *(const half8v*)(ap);                                           \
    af[1] = *(const half8v*)(ap + 1024);                                    \
    af[2] = *(const half8v*)(ap + 2048);                                    \
    af[3] = *(const half8v*)(ap + 3072);                                    \
  } while (0)
#define LD_BF(buf, ks)                                                      \
  do {                                                                      \
    const unsigned short* bp = &Bs[buf][0] +                                \
        (wcn * 64 + lr) * 64 + (((ks) ? (ck0 ^ 4) : ck0)) * 8;              \
    bf[0] = *(const half8v*)(bp);                                           \
    bf[1] = *(const half8v*)(bp + 1024);                                    \
    bf[2] = *(const half8v*)(bp + 2048);                                    \
    bf[3] = *(const half8v*)(bp + 3072);                                    \
  } while (0)
#define MROW(mg, i)                                                         \
  acc[(mg)*4+(i)][0] = __builtin_amdgcn_mfma_f32_16x16x32_f16(bf[0], af[i], acc[(mg)*4+(i)][0], 0, 0, 0); \
  acc[(mg)*4+(i)][1] = __builtin_amdgcn_mfma_f32_16x16x32_f16(bf[1], af[i], acc[(mg)*4+(i)][1], 0, 0, 0); \
  acc[(mg)*4+(i)][2] = __builtin_amdgcn_mfma_f32_16x16x32_f16(bf[2], af[i], acc[(mg)*4+(i)][2], 0, 0, 0); \
  acc[(mg)*4+(i)][3] = __builtin_amdgcn_mfma_f32_16x16x32_f16(bf[3], af[i], acc[(mg)*4+(i)][3], 0, 0, 0);
#define MFMA16(mg)                                                          \
  do {                                                                      \
    __builtin_amdgcn_s_setprio(1);                                          \
    MROW(mg, 0); MROW(mg, 1); MROW(mg, 2); MROW(mg, 3);                     \
    __builtin_amdgcn_s_setprio(0);                                          \
  } while (0)

  for (int it2 = 0; it2 < NIT; ++it2) {
    const bool more = (it2 + 1 < NIT);
    const int keven = 2 * it2;
    half8v af[4], bf[4];
    // p1: reads buf0; stage A(odd)->buf1 units 0,1
    LD_BF(0, 0); LD_AF(0, 0, 0);
    SA_U(1, keven + 1, 0); SA_U(1, keven + 1, 1);
    BARS;
    MFMA16(0);
    BARS;
    // p2: stage A(odd)->buf1 units 2,3
    LD_AF(0, 1, 0);
    SA_U(1, keven + 1, 2); SA_U(1, keven + 1, 3);
    BARS;
    MFMA16(1);
    BARS;
    // p3
    LD_BF(0, 1); LD_AF(0, 0, 1);
    BARS;
    MFMA16(0);
    BARS;
    // p4: stage B(next even)->buf0 units 0,1 (B buf0 dead since p3);
    // vmcnt(2): A-odd + B-odd-prev drained, only the 2 new B in flight.
    LD_AF(0, 1, 1);
    if (more) {
      SB_U(0, keven + 2, 0); SB_U(0, keven + 2, 1);
      asm volatile("s_waitcnt vmcnt(2)" ::: "memory");
    } else {
      asm volatile("s_waitcnt vmcnt(0)" ::: "memory");
    }
    BARS;
    MFMA16(1);
    BARS;
    // p5: stage B(next even)->buf0 units 2,3
    LD_BF(1, 0); LD_AF(1, 0, 0);
    if (more) { SB_U(0, keven + 2, 2); SB_U(0, keven + 2, 3); }
    BARS;
    MFMA16(0);
    BARS;
    // p6: stage A(next even)->buf0 units 0,1 (A buf0 dead since p4)
    LD_AF(1, 1, 0);
    if (more) { SA_U(0, keven + 2, 0); SA_U(0, keven + 2, 1); }
    BARS;
    MFMA16(1);
    BARS;
    // p7: stage A(next even)->buf0 units 2,3
    LD_BF(1, 1); LD_AF(1, 0, 1);
    if (more) { SA_U(0, keven + 2, 2); SA_U(0, keven + 2, 3); }
    BARS;
    MFMA16(0);
    BARS;
    // p8: stage B(next odd)->buf1 all 4 (B buf1 dead since p7);
    // vmcnt(4): B-even + A-even drained, only the 4 new B in flight.
    LD_AF(1, 1, 1);
    if (more) {
      SB_U(1, keven + 3, 0); SB_U(1, keven + 3, 1);
      SB_U(1, keven + 3, 2); SB_U(1, keven + 3, 3);
      asm volatile("s_waitcnt vmcnt(4)" ::: "memory");
    }
    BARS;
    MFMA16(1);
    BARS;
  }
#undef SA_U
#undef SB_U
#undef LD_AF
#undef LD_BF
#undef MROW
#undef MFMA16
#undef BARS

  const int cr = (lane >> 4) * 4;   // channel offset (4 contiguous)
  const int cc = lane & 15;         // token offset

  if constexpr (MODE == 0) {
    #pragma unroll
    for (int j = 0; j < 4; ++j) {
      const int n = n0 + wcn * 64 + j * 16 + cr;
      const float4 b4 = *reinterpret_cast<const float4*>(bias + n);
      #pragma unroll
      for (int i = 0; i < 8; ++i) {
        const int m = m0 + wr * 128 + i * 16 + cc;
        float4 r;
        r.x = acc[i][j][0] + b4.x;
        r.y = acc[i][j][1] + b4.y;
        r.z = acc[i][j][2] + b4.z;
        r.w = acc[i][j][3] + b4.w;
        *reinterpret_cast<float4*>(Cf + (size_t)m * N + n) = r;
      }
    }
  } else {
    const int mb   = m0 + wr * 128;
    const int btok = mb >> 12;
    const int hr0  = (mb >> 6) & 63;
    #pragma unroll
    for (int j = 0; j < 4; ++j) {
      const int nb    = n0 + wcn * 64 + j * 16 + cr;
      const int tq    = nb >> 9;
      const int halfc = (nb >> 8) & 1;
      const int nn    = (nb & 255) >> 5;
      const int ch4   = nb & 31;
      const int headbase = tq * 16777216 + halfc * 8388608 +
                           (btok * 8 + nn) * 131072 + ch4;
      #pragma unroll
      for (int i = 0; i < 8; ++i) {
        const int hrow = hr0 + (i >> 2);
        const int wpix = (i & 3) * 16 + cc;
        const int off = halfc ? (hrow * 2048 + wpix * 32)
                              : ((hrow >> 3) * 16384 + wpix * 256 + (hrow & 7) * 32);
        uint2 r;
        r.x = pkrtz_u32(acc[i][j][0], acc[i][j][1]);
        r.y = pkrtz_u32(acc[i][j][2], acc[i][j][3]);
        *reinterpret_cast<uint2*>(Cq + headbase + off) = r;
      }
    }
  }
}

// ---------- GEMM2: out = attn_out(f16) @ w_proj(f16)^T + bias -> f32 ----------
// R9-proven 128x128 2-phase, gload_lds, counted vmcnt(4); grid 1024 = 4/CU TLP.
__global__ __launch_bounds__(256) void gemm_proj(
    const unsigned short* __restrict__ A,
    const unsigned short* __restrict__ B,
    float* __restrict__ Cf,
    const float* __restrict__ bias)
{
  constexpr int K = 512, N = 512;
  __shared__ unsigned short As[2][128 * 32];
  __shared__ unsigned short Bs[2][128 * 32];
  const int tid  = threadIdx.x;
  const int gn   = N >> 7;                 // 4
  const int cpx  = gridDim.x >> 3;
  const int bid  = blockIdx.x;
  const int wgid = (bid & 7) * cpx + (bid >> 3);
  const int m0   = (wgid / gn) * 128;
  const int n0   = (wgid % gn) * 128;
  const int wave = tid >> 6, lane = tid & 63;
  const int wr = wave >> 1, wc = wave & 1;
  const int sr = tid >> 2;
  const int sc = ((tid & 3) ^ ((tid >> 3) & 3)) * 8;
  const size_t aBase0 = (size_t)(m0 + sr) * K + sc;
  const size_t aBase1 = (size_t)(m0 + 64 + sr) * K + sc;
  const size_t bBase0 = (size_t)(n0 + sr) * K + sc;
  const size_t bBase1 = (size_t)(n0 + 64 + sr) * K + sc;
  char* ldsA = (char*)(&As[0][0]) + (tid & ~63) * 16;
  char* ldsB = (char*)(&Bs[0][0]) + (tid & ~63) * 16;

#define STAGE_P(bsel, kofs)                                        \
  do {                                                             \
    GLOAD_LDS16(A + aBase0 + (kofs), ldsA + (bsel) * 8192);        \
    GLOAD_LDS16(A + aBase1 + (kofs), ldsA + (bsel) * 8192 + 4096); \
    GLOAD_LDS16(B + bBase0 + (kofs), ldsB + (bsel) * 8192);        \
    GLOAD_LDS16(B + bBase1 + (kofs), ldsB + (bsel) * 8192 + 4096); \
  } while (0)

  STAGE_P(0, 0);

  f32x4 acc[4][4];
  const f32x4 zero = {0.f, 0.f, 0.f, 0.f};
  #pragma unroll
  for (int i = 0; i < 4; ++i)
    #pragma unroll
    for (int j = 0; j < 4; ++j) acc[i][j] = zero;

  const int lr   = lane & 15;
  const int slot = (lane >> 4) ^ ((lr >> 1) & 3);

  auto compute = [&](const unsigned short* Asb, const unsigned short* Bsb) {
    half8v af[4], bfr[4];
    #pragma unroll
    for (int i = 0; i < 4; ++i)
      af[i] = *reinterpret_cast<const half8v*>(Asb + (wr * 64 + i * 16 + lr) * 32 + slot * 8);
    #pragma unroll
    for (int j = 0; j < 4; ++j)
      bfr[j] = *reinterpret_cast<const half8v*>(Bsb + (wc * 64 + j * 16 + lr) * 32 + slot * 8);
    __builtin_amdgcn_s_setprio(1);
    #pragma unroll
    for (int i = 0; i < 4; ++i)
      #pragma unroll
      for (int j = 0; j < 4; ++j)
        acc[i][j] = __builtin_amdgcn_mfma_f32_16x16x32_f16(bfr[j], af[i], acc[i][j], 0, 0, 0);
    __builtin_amdgcn_s_setprio(0);
  };

  const int nt = K >> 5;
  for (int t = 0; t < nt - 1; ++t) {
    STAGE_P((t + 1) & 1, (t + 1) * 32);
    asm volatile("s_waitcnt vmcnt(4)" ::: "memory");
    __builtin_amdgcn_s_barrier();
    __builtin_amdgcn_sched_barrier(0);
    compute(&As[t & 1][0], &Bs[t & 1][0]);
    __builtin_amdgcn_s_barrier();
    __builtin_amdgcn_sched_barrier(0);
  }
  asm volatile("s_waitcnt vmcnt(0)" ::: "memory");
  __builtin_amdgcn_s_barrier();
  __builtin_amdgcn_sched_barrier(0);
  compute(&As[(nt - 1) & 1][0], &Bs[(nt - 1) & 1][0]);
#undef STAGE_P

  const int cr = (lane >> 4) * 4;
  const int cc = lane & 15;
  #pragma unroll
  for (int j = 0; j < 4; ++j) {
    const int n = n0 + wc * 64 + j * 16 + cr;
    const float4 b4 = *reinterpret_cast<const float4*>(bias + n);
    #pragma unroll
    for (int i = 0; i < 4; ++i) {
      const int m = m0 + wr * 64 + i * 16 + cc;
      float4 r;
      r.x = acc[i][j][0] + b4.x;
      r.y = acc[i][j][1] + b4.y;
      r.z = acc[i][j][2] + b4.z;
      r.w = acc[i][j][3] + b4.w;
      *reinterpret_cast<float4*>(Cf + (size_t)m * N + n) = r;
    }
  }
}

// ---------- stripe attention + LePE, TWO windows per wave ----------
__global__ __launch_bounds__(256) void attn_lepe(
    const unsigned short* __restrict__ qkvp,
    const unsigned short* __restrict__ wlep,
    unsigned short* __restrict__ outp)
{
  const int gw   = (int)((blockIdx.x * 256 + threadIdx.x) >> 6);  // pair index
  const int lane = threadIdx.x & 63;
  const int half = gw >> 14;
  const int id   = gw & 16383;
  const int b    = id >> 11;
  const int n    = (id >> 8) & 7;
  int h0, w0;
  if (half == 0) { h0 = ((id >> 5) & 7) * 8; w0 = (id & 31) * 2; }
  else           { h0 = ((id >> 3) & 31) * 2; w0 = (id & 7) * 8; }
  const int baseA = qkv_idx(half, b, n, h0, w0);
  const int dWin  = (half == 0) ? 256 : 2048;
  const int baseB = baseA + dWin;

  // ---- QK^T for both windows: lane = (qr, kr) ----
  const int qr = lane >> 3, kr = lane & 7;
  const unsigned short* qA = qkvp + baseA + qr * 32;
  const unsigned short* kA = qkvp + 16777216 + baseA + kr * 32;
  float sA = 0.f, sB = 0.f;
  #pragma unroll
  for (int c = 0; c < 4; ++c) {
    const u32x4 qa = *reinterpret_cast<const u32x4*>(qA + c * 8);
    const u32x4 ka = *reinterpret_cast<const u32x4*>(kA + c * 8);
    const u32x4 qb = *reinterpret_cast<const u32x4*>(qA + dWin + c * 8);
    const u32x4 kb = *reinterpret_cast<const u32x4*>(kA + dWin + c * 8);
    #pragma unroll
    for (int e = 0; e < 4; ++e) {
      sA = __builtin_amdgcn_fdot2(bch2(qa[e]), bch2(ka[e]), sA, false);
      sB = __builtin_amdgcn_fdot2(bch2(qb[e]), bch2(kb[e]), sB, false);
    }
  }
  const float scl = 0.17677669529663687f;
  const float pA = __expf(sA * scl);
  const float pB = __expf(sB * scl);
  float denA = pA, denB = pB;
  denA += __shfl_xor(denA, 1); denA += __shfl_xor(denA, 2); denA += __shfl_xor(denA, 4);
  denB += __shfl_xor(denB, 1); denB += __shfl_xor(denB, 2); denB += __shfl_xor(denB, 4);
  const float aAv = pA * __builtin_amdgcn_rcpf(denA);
  const float aBv = pB * __builtin_amdgcn_rcpf(denB);
  const uint32_t adu = pkrtz_u32(aAv, aBv);   // lo = winA, hi = winB

  // ---- PV: lane = (qr2, win, dgrp); 16B vectors over 8 channels ----
  const int dgrp = lane & 3;
  const int win  = (lane >> 2) & 1;
  const int qr2  = lane >> 3;
  const int d0   = dgrp * 8;
  const int mybase = win ? baseB : baseA;
  const unsigned short* vwin = qkvp + 33554432 + mybase;

  half2v o01 = {0,0}, o23 = {0,0}, o45 = {0,0}, o67 = {0,0};
  #pragma unroll
  for (int k = 0; k < 8; ++k) {
    const uint32_t pairw = (uint32_t)__shfl((int)adu, qr2 * 8 + k);
    const half2v ph = bch2(pairw);
    const _Float16 av = win ? ph.y : ph.x;
    const half2v ak2 = {av, av};
    const u32x4 vv = *reinterpret_cast<const u32x4*>(vwin + k * 32 + d0);
    o01 += ak2 * bch2(vv[0]);
    o23 += ak2 * bch2(vv[1]);
    o45 += ak2 * bch2(vv[2]);
    o67 += ak2 * bch2(vv[3]);
  }

  // ---- LePE: depthwise 3x3 on v (zero-pad SAME) at this lane's pixel ----
  const int hq = (half == 0) ? (h0 + qr2) : (h0 + win);
  const int wq = (half == 0) ? (w0 + win) : (w0 + qr2);
  const unsigned short* vplane = qkvp + 33554432;
  const unsigned short* wl = wlep + half * 2304 + n * 32 + d0;
  half2v l01 = {0,0}, l23 = {0,0}, l45 = {0,0}, l67 = {0,0};
  #pragma unroll
  for (int dy = -1; dy <= 1; ++dy) {
    #pragma unroll
    for (int dx = -1; dx <= 1; ++dx) {
      const int hh = hq + dy, ww = wq + dx;
      u32x4 vv = {0u, 0u, 0u, 0u};
      if ((unsigned)hh < 64u && (unsigned)ww < 64u)
        vv = *reinterpret_cast<const u32x4*>(vplane + qkv_idx(half, b, n, hh, ww) + d0);
      const u32x4 wt = *reinterpret_cast<const u32x4*>(wl + ((dy + 1) * 3 + dx + 1) * 256);
      l01 += bch2(wt[0]) * bch2(vv[0]);
      l23 += bch2(wt[1]) * bch2(vv[1]);
      l45 += bch2(wt[2]) * bch2(vv[2]);
      l67 += bch2(wt[3]) * bch2(vv[3]);
    }
  }

  // ---- store token-major for GEMM2 (16B per lane) ----
  const int m = b * 4096 + hq * 64 + wq;
  const int chan0 = half * 256 + n * 32;
  u32x4 r;
  r[0] = __builtin_bit_cast(uint32_t, (half2v)(o01 + l01));
  r[1] = __builtin_bit_cast(uint32_t, (half2v)(o23 + l23));
  r[2] = __builtin_bit_cast(uint32_t, (half2v)(o45 + l45));
  r[3] = __builtin_bit_cast(uint32_t, (half2v)(o67 + l67));
  *reinterpret_cast<u32x4*>(outp + (size_t)m * 512 + chan0 + d0) = r;
}

// ---------- launch ----------
extern "C" void kernel_launch(void* const* d_in, const int* in_sizes, int n_in,
                              void* d_out, int out_size, void* d_ws, size_t ws_size,
                              hipStream_t stream) {
  const float* x      = (const float*)d_in[0];   // (8, 4096, 512)
  const float* w_qkv  = (const float*)d_in[1];   // (1536, 512)
  const float* w_proj = (const float*)d_in[2];   // (512, 512)
  const float* b_proj = (const float*)d_in[3];   // (512,)
  const float* lepe_h = (const float*)d_in[4];   // (3,3,1,256)
  const float* lepe_v = (const float*)d_in[5];   // (3,3,1,256)
  float* out = (float*)d_out;                    // (8, 4096, 512) f32

  char* ws = (char*)d_ws;
  unsigned short* qkv_p   = (unsigned short*)ws;                 // 96MB: q|k|v window-major
  unsigned short* xh      = (unsigned short*)(ws + 100663296);   // 32MB: x f16; reused as attn_out
  unsigned short* wqkv_h  = (unsigned short*)(ws + 134217728);   // 1536*512 f16
  unsigned short* wproj_h = (unsigned short*)(ws + 135790592);   // 512*512 f16
  unsigned short* wlep_h  = (unsigned short*)(ws + 136314880);   // 2*9*256 f16

  // all casts in one launch: 4194304 + 196608 + 65536 + 576 + 576 float4s
  cvt_all<<<17413, 256, 0, stream>>>(x, w_qkv, w_proj, lepe_h, lepe_v,
                                     xh, wqkv_h, wproj_h, wlep_h);

  // qkv = x @ w_qkv^T -> window-major f16 (8-phase 256^2, spread staging)
  gemm8<1><<<768, 512, 0, stream>>>(
      xh, wqkv_h, qkv_p, nullptr, nullptr, 32768, 1536);

  // stripe attention + LePE -> attn_out token-major (xh dead -> reuse)
  attn_lepe<<<8192, 256, 0, stream>>>(qkv_p, wlep_h, xh);

  // out = attn_out @ w_proj^T + b_proj -> f32 (128^2 2-phase; grid 1024)
  gemm_proj<<<1024, 256, 0, stream>>>(xh, wproj_h, out, b_proj);
}

// Round 18
// 169.916 us; speedup vs baseline: 4.5432x; 1.0154x over previous
//
#include <hip/hip_runtime.h>
#include <hip/hip_bf16.h>
#include <stdint.h>

// ---------- types ----------
typedef _Float16 half2v __attribute__((ext_vector_type(2)));
typedef _Float16 half8v __attribute__((ext_vector_type(8)));
typedef uint32_t u32x4  __attribute__((ext_vector_type(4)));
typedef float    f32x4  __attribute__((ext_vector_type(4)));

__device__ __forceinline__ unsigned short f2h(float f) {
  _Float16 h = (_Float16)f;
  return __builtin_bit_cast(unsigned short, h);
}
__device__ __forceinline__ half2v bch2(uint32_t u) {
  return __builtin_bit_cast(half2v, u);
}
__device__ __forceinline__ uint32_t pkrtz_u32(float a, float b) {
  return __builtin_bit_cast(uint32_t, __builtin_amdgcn_cvt_pkrtz(a, b));
}

// Window-major qkv layout (channel 0 of head n, pixel (h,w)).
__device__ __forceinline__ int qkv_idx(int half, int b, int n, int h, int w) {
  int idx = half * 8388608 + (b * 8 + n) * 131072;
  idx += (half == 0) ? ((h >> 3) * 16384 + w * 256 + (h & 7) * 32)
                     : (h * 2048 + w * 32);
  return idx;
}

// async global->LDS, 16 bytes per lane. lbase = wave-uniform base.
#define GLOAD_LDS16(gsrc, lbase)                                          \
  __builtin_amdgcn_global_load_lds(                                       \
      (const __attribute__((address_space(1))) uint32_t*)(gsrc),          \
      (__attribute__((address_space(3))) uint32_t*)(lbase), 16, 0, 0)

// ---------- ONE cast kernel: x (f32->f16) + all weights ----------
__global__ __launch_bounds__(256) void cvt_all(
    const float* __restrict__ x,
    const float* __restrict__ wqkv, const float* __restrict__ wproj,
    const float* __restrict__ lh,   const float* __restrict__ lv,
    unsigned short* __restrict__ ox,
    unsigned short* __restrict__ owqkv, unsigned short* __restrict__ owproj,
    unsigned short* __restrict__ owlep)
{
  int i = blockIdx.x * 256 + threadIdx.x;   // float4 index
  const float* src; unsigned short* dst; int off;
  if (i < 4194304)      { src = x;     dst = ox;           off = i; }
  else if ((i -= 4194304) < 196608) { src = wqkv;  dst = owqkv;  off = i; }
  else if ((i -= 196608) < 65536)   { src = wproj; dst = owproj; off = i; }
  else if ((i -= 65536) < 576)      { src = lh;    dst = owlep;  off = i; }
  else if ((i -= 576) < 576)        { src = lv;    dst = owlep + 2304; off = i; }
  else return;
  float4 f = reinterpret_cast<const float4*>(src)[off];
  ushort4 u;
  u.x = f2h(f.x); u.y = f2h(f.y); u.z = f2h(f.z); u.w = f2h(f.w);
  reinterpret_cast<ushort4*>(dst)[off] = u;
}

// ---------- GEMM1: persistent 8-phase 256^2 f16 ----------
// Grid 256 = exactly 1 block/CU, zero dispatch tail. Each block owns m-tile
// mt = wgid>>1 and sweeps 3 n-tiles (nh = wgid&1 selects which half of the 6).
// K-loop = R17's verified 8-phase body (spread staging, counted vmcnt).
// Pass boundary: issue next pass's 12-load prologue BEFORE the epilogue's
// 32 scattered stores (load latency hides under store issue), then
// vmcnt(0)+barrier -> next K-loop enters with 0 outstanding (counted-entry
// invariant "<=4 outstanding" trivially satisfied; p4/p8 arithmetic re-checked
// for the 0-entry case). A staged from L2 (same panel 6x, XCD-swizzled).
__global__ __launch_bounds__(512, 2) void gemm8p(
    const unsigned short* __restrict__ A,
    const unsigned short* __restrict__ Bm,
    unsigned short* __restrict__ Cq)
{
  constexpr int K = 512;
  constexpr int NIT = 4;                    // K / 128
  __shared__ unsigned short As[2][256 * 64];   // 2 x 32KB
  __shared__ unsigned short Bs[2][256 * 64];   // 2 x 32KB
  const int tid  = threadIdx.x;
  const int cpx  = gridDim.x >> 3;                 // 32
  const int bid  = blockIdx.x;
  const int wgid = (bid & 7) * cpx + (bid >> 3);   // bijective (grid%8==0)
  const int mt   = wgid >> 1;        // 0..127
  const int nh   = wgid & 1;         // n-tile half: tiles nh*3 .. nh*3+2
  const int m0   = mt * 256;
  const int wave = tid >> 6, lane = tid & 63;
  const int wr  = wave >> 2;        // 0..1 (128 M-rows)
  const int wcn = wave & 3;         // 0..3 (64 N-cols)

  const int srow = tid >> 3;
  const int schk = ((tid & 7) ^ (srow & 7)) * 8;
  const size_t aSrc = (size_t)(m0 + srow) * K + schk;
  size_t bSrc = (size_t)(nh * 768 + srow) * K + schk;   // pass0 n0 = nh*768
  char* ldsA = (char*)(&As[0][0]) + (tid & ~63) * 16;
  char* ldsB = (char*)(&Bs[0][0]) + (tid & ~63) * 16;

#define SA_U(b, kt, u)                                                      \
  GLOAD_LDS16(A + aSrc + (size_t)(u) * 64 * K + (size_t)(kt) * 64,          \
              ldsA + (b) * 32768 + (u) * 8192)
#define SB_U(b, kt, u, bS)                                                  \
  GLOAD_LDS16(Bm + (bS) + (size_t)(u) * 64 * K + (size_t)(kt) * 64,         \
              ldsB + (b) * 32768 + (u) * 8192)
#define BARS                                                                \
  __builtin_amdgcn_s_barrier();                                             \
  __builtin_amdgcn_sched_barrier(0)

  // initial prologue: tile0 (buf0) full + tile1 B (buf1) in flight
  SA_U(0, 0, 0); SA_U(0, 0, 1); SA_U(0, 0, 2); SA_U(0, 0, 3);
  SB_U(0, 0, 0, bSrc); SB_U(0, 0, 1, bSrc); SB_U(0, 0, 2, bSrc); SB_U(0, 0, 3, bSrc);
  SB_U(1, 1, 0, bSrc); SB_U(1, 1, 1, bSrc); SB_U(1, 1, 2, bSrc); SB_U(1, 1, 3, bSrc);
  asm volatile("s_waitcnt vmcnt(4)" ::: "memory");
  BARS;

  const int lr  = lane & 15;
  const int kg  = lane >> 4;
  const int ck0 = kg ^ (lr & 7);            // k-step0 slot; k-step1 = ck0^4

#define LD_AF(buf, mg, ks)                                                  \
  do {                                                                      \
    const unsigned short* ap = &As[buf][0] +                                \
        (wr * 128 + (mg) * 64 + lr) * 64 + (((ks) ? (ck0 ^ 4) : ck0)) * 8;  \
    af[0] = *(const half8v*)(ap);                                           \
    af[1] = *(const half8v*)(ap + 1024);                                    \
    af[2] = *(const half8v*)(ap + 2048);                                    \
    af[3] = *(const half8v*)(ap + 3072);                                    \
  } while (0)
#define LD_BF(buf, ks)                                                      \
  do {                                                                      \
    const unsigned short* bp = &Bs[buf][0] +                                \
        (wcn * 64 + lr) * 64 + (((ks) ? (ck0 ^ 4) : ck0)) * 8;              \
    bf[0] = *(const half8v*)(bp);                                           \
    bf[1] = *(const half8v*)(bp + 1024);                                    \
    bf[2] = *(const half8v*)(bp + 2048);                                    \
    bf[3] = *(const half8v*)(bp + 3072);                                    \
  } while (0)
#define MROW(mg, i)                                                         \
  acc[(mg)*4+(i)][0] = __builtin_amdgcn_mfma_f32_16x16x32_f16(bf[0], af[i], acc[(mg)*4+(i)][0], 0, 0, 0); \
  acc[(mg)*4+(i)][1] = __builtin_amdgcn_mfma_f32_16x16x32_f16(bf[1], af[i], acc[(mg)*4+(i)][1], 0, 0, 0); \
  acc[(mg)*4+(i)][2] = __builtin_amdgcn_mfma_f32_16x16x32_f16(bf[2], af[i], acc[(mg)*4+(i)][2], 0, 0, 0); \
  acc[(mg)*4+(i)][3] = __builtin_amdgcn_mfma_f32_16x16x32_f16(bf[3], af[i], acc[(mg)*4+(i)][3], 0, 0, 0);
#define MFMA16(mg)                                                          \
  do {                                                                      \
    __builtin_amdgcn_s_setprio(1);                                          \
    MROW(mg, 0); MROW(mg, 1); MROW(mg, 2); MROW(mg, 3);                     \
    __builtin_amdgcn_s_setprio(0);                                          \
  } while (0)

  f32x4 acc[8][4];
  const f32x4 zero = {0.f, 0.f, 0.f, 0.f};

  #pragma unroll 1
  for (int pass = 0; pass < 3; ++pass) {
    const int n0 = (nh * 3 + pass) * 256;
    #pragma unroll
    for (int i = 0; i < 8; ++i)
      #pragma unroll
      for (int j = 0; j < 4; ++j) acc[i][j] = zero;

    for (int it2 = 0; it2 < NIT; ++it2) {
      const bool more = (it2 + 1 < NIT);
      const int keven = 2 * it2;
      half8v af[4], bf[4];
      // p1: reads buf0; stage A(odd)->buf1 units 0,1
      LD_BF(0, 0); LD_AF(0, 0, 0);
      SA_U(1, keven + 1, 0); SA_U(1, keven + 1, 1);
      BARS;
      MFMA16(0);
      BARS;
      // p2: stage A(odd)->buf1 units 2,3
      LD_AF(0, 1, 0);
      SA_U(1, keven + 1, 2); SA_U(1, keven + 1, 3);
      BARS;
      MFMA16(1);
      BARS;
      // p3
      LD_BF(0, 1); LD_AF(0, 0, 1);
      BARS;
      MFMA16(0);
      BARS;
      // p4: stage B(next even)->buf0 units 0,1; vmcnt(2)
      LD_AF(0, 1, 1);
      if (more) {
        SB_U(0, keven + 2, 0, bSrc); SB_U(0, keven + 2, 1, bSrc);
        asm volatile("s_waitcnt vmcnt(2)" ::: "memory");
      } else {
        asm volatile("s_waitcnt vmcnt(0)" ::: "memory");
      }
      BARS;
      MFMA16(1);
      BARS;
      // p5: stage B(next even)->buf0 units 2,3
      LD_BF(1, 0); LD_AF(1, 0, 0);
      if (more) { SB_U(0, keven + 2, 2, bSrc); SB_U(0, keven + 2, 3, bSrc); }
      BARS;
      MFMA16(0);
      BARS;
      // p6: stage A(next even)->buf0 units 0,1
      LD_AF(1, 1, 0);
      if (more) { SA_U(0, keven + 2, 0); SA_U(0, keven + 2, 1); }
      BARS;
      MFMA16(1);
      BARS;
      // p7: stage A(next even)->buf0 units 2,3
      LD_BF(1, 1); LD_AF(1, 0, 1);
      if (more) { SA_U(0, keven + 2, 2); SA_U(0, keven + 2, 3); }
      BARS;
      MFMA16(0);
      BARS;
      // p8: stage B(next odd)->buf1 all 4; vmcnt(4)
      LD_AF(1, 1, 1);
      if (more) {
        SB_U(1, keven + 3, 0, bSrc); SB_U(1, keven + 3, 1, bSrc);
        SB_U(1, keven + 3, 2, bSrc); SB_U(1, keven + 3, 3, bSrc);
        asm volatile("s_waitcnt vmcnt(4)" ::: "memory");
      }
      BARS;
      MFMA16(1);
      BARS;
    }
    // pass end: 0 VMEM outstanding; all waves past reading both buffers.

    if (pass < 2) {
      // prologue for next pass BEFORE epilogue: loads hide under store issue
      const size_t bSrcN = bSrc + (size_t)256 * K;
      SA_U(0, 0, 0); SA_U(0, 0, 1); SA_U(0, 0, 2); SA_U(0, 0, 3);
      SB_U(0, 0, 0, bSrcN); SB_U(0, 0, 1, bSrcN); SB_U(0, 0, 2, bSrcN); SB_U(0, 0, 3, bSrcN);
      SB_U(1, 1, 0, bSrcN); SB_U(1, 1, 1, bSrcN); SB_U(1, 1, 2, bSrcN); SB_U(1, 1, 3, bSrcN);
      bSrc = bSrcN;
    }

    // epilogue: scatter to window-major qkv regions
    {
      const int cr = (lane >> 4) * 4;
      const int cc = lane & 15;
      const int mb   = m0 + wr * 128;
      const int btok = mb >> 12;
      const int hr0  = (mb >> 6) & 63;
      #pragma unroll
      for (int j = 0; j < 4; ++j) {
        const int nb    = n0 + wcn * 64 + j * 16 + cr;
        const int tq    = nb >> 9;
        const int halfc = (nb >> 8) & 1;
        const int nn    = (nb & 255) >> 5;
        const int ch4   = nb & 31;
        const int headbase = tq * 16777216 + halfc * 8388608 +
                             (btok * 8 + nn) * 131072 + ch4;
        #pragma unroll
        for (int i = 0; i < 8; ++i) {
          const int hrow = hr0 + (i >> 2);
          const int wpix = (i & 3) * 16 + cc;
          const int off = halfc ? (hrow * 2048 + wpix * 32)
                                : ((hrow >> 3) * 16384 + wpix * 256 + (hrow & 7) * 32);
          uint2 r;
          r.x = pkrtz_u32(acc[i][j][0], acc[i][j][1]);
          r.y = pkrtz_u32(acc[i][j][2], acc[i][j][3]);
          *reinterpret_cast<uint2*>(Cq + headbase + off) = r;
        }
      }
    }

    if (pass < 2) {
      asm volatile("s_waitcnt vmcnt(0)" ::: "memory");  // prologue landed
      BARS;                                             // all waves see tiles
    }
  }
#undef SA_U
#undef SB_U
#undef LD_AF
#undef LD_BF
#undef MROW
#undef MFMA16
#undef BARS
}

// ---------- GEMM2: out = attn_out(f16) @ w_proj(f16)^T + bias -> f32 ----------
// R9-proven 128x128 2-phase, gload_lds, counted vmcnt(4); grid 1024 = 4/CU TLP.
__global__ __launch_bounds__(256) void gemm_proj(
    const unsigned short* __restrict__ A,
    const unsigned short* __restrict__ B,
    float* __restrict__ Cf,
    const float* __restrict__ bias)
{
  constexpr int K = 512, N = 512;
  __shared__ unsigned short As[2][128 * 32];
  __shared__ unsigned short Bs[2][128 * 32];
  const int tid  = threadIdx.x;
  const int gn   = N >> 7;                 // 4
  const int cpx  = gridDim.x >> 3;
  const int bid  = blockIdx.x;
  const int wgid = (bid & 7) * cpx + (bid >> 3);
  const int m0   = (wgid / gn) * 128;
  const int n0   = (wgid % gn) * 128;
  const int wave = tid >> 6, lane = tid & 63;
  const int wr = wave >> 1, wc = wave & 1;
  const int sr = tid >> 2;
  const int sc = ((tid & 3) ^ ((tid >> 3) & 3)) * 8;
  const size_t aBase0 = (size_t)(m0 + sr) * K + sc;
  const size_t aBase1 = (size_t)(m0 + 64 + sr) * K + sc;
  const size_t bBase0 = (size_t)(n0 + sr) * K + sc;
  const size_t bBase1 = (size_t)(n0 + 64 + sr) * K + sc;
  char* ldsA = (char*)(&As[0][0]) + (tid & ~63) * 16;
  char* ldsB = (char*)(&Bs[0][0]) + (tid & ~63) * 16;

#define STAGE_P(bsel, kofs)                                        \
  do {                                                             \
    GLOAD_LDS16(A + aBase0 + (kofs), ldsA + (bsel) * 8192);        \
    GLOAD_LDS16(A + aBase1 + (kofs), ldsA + (bsel) * 8192 + 4096); \
    GLOAD_LDS16(B + bBase0 + (kofs), ldsB + (bsel) * 8192);        \
    GLOAD_LDS16(B + bBase1 + (kofs), ldsB + (bsel) * 8192 + 4096); \
  } while (0)

  STAGE_P(0, 0);

  f32x4 acc[4][4];
  const f32x4 zero = {0.f, 0.f, 0.f, 0.f};
  #pragma unroll
  for (int i = 0; i < 4; ++i)
    #pragma unroll
    for (int j = 0; j < 4; ++j) acc[i][j] = zero;

  const int lr   = lane & 15;
  const int slot = (lane >> 4) ^ ((lr >> 1) & 3);

  auto compute = [&](const unsigned short* Asb, const unsigned short* Bsb) {
    half8v af[4], bfr[4];
    #pragma unroll
    for (int i = 0; i < 4; ++i)
      af[i] = *reinterpret_cast<const half8v*>(Asb + (wr * 64 + i * 16 + lr) * 32 + slot * 8);
    #pragma unroll
    for (int j = 0; j < 4; ++j)
      bfr[j] = *reinterpret_cast<const half8v*>(Bsb + (wc * 64 + j * 16 + lr) * 32 + slot * 8);
    __builtin_amdgcn_s_setprio(1);
    #pragma unroll
    for (int i = 0; i < 4; ++i)
      #pragma unroll
      for (int j = 0; j < 4; ++j)
        acc[i][j] = __builtin_amdgcn_mfma_f32_16x16x32_f16(bfr[j], af[i], acc[i][j], 0, 0, 0);
    __builtin_amdgcn_s_setprio(0);
  };

  const int nt = K >> 5;
  for (int t = 0; t < nt - 1; ++t) {
    STAGE_P((t + 1) & 1, (t + 1) * 32);
    asm volatile("s_waitcnt vmcnt(4)" ::: "memory");
    __builtin_amdgcn_s_barrier();
    __builtin_amdgcn_sched_barrier(0);
    compute(&As[t & 1][0], &Bs[t & 1][0]);
    __builtin_amdgcn_s_barrier();
    __builtin_amdgcn_sched_barrier(0);
  }
  asm volatile("s_waitcnt vmcnt(0)" ::: "memory");
  __builtin_amdgcn_s_barrier();
  __builtin_amdgcn_sched_barrier(0);
  compute(&As[(nt - 1) & 1][0], &Bs[(nt - 1) & 1][0]);
#undef STAGE_P

  const int cr = (lane >> 4) * 4;
  const int cc = lane & 15;
  #pragma unroll
  for (int j = 0; j < 4; ++j) {
    const int n = n0 + wc * 64 + j * 16 + cr;
    const float4 b4 = *reinterpret_cast<const float4*>(bias + n);
    #pragma unroll
    for (int i = 0; i < 4; ++i) {
      const int m = m0 + wr * 64 + i * 16 + cc;
      float4 r;
      r.x = acc[i][j][0] + b4.x;
      r.y = acc[i][j][1] + b4.y;
      r.z = acc[i][j][2] + b4.z;
      r.w = acc[i][j][3] + b4.w;
      *reinterpret_cast<float4*>(Cf + (size_t)m * N + n) = r;
    }
  }
}

// ---------- stripe attention + LePE, TWO windows per wave ----------
__global__ __launch_bounds__(256) void attn_lepe(
    const unsigned short* __restrict__ qkvp,
    const unsigned short* __restrict__ wlep,
    unsigned short* __restrict__ outp)
{
  const int gw   = (int)((blockIdx.x * 256 + threadIdx.x) >> 6);  // pair index
  const int lane = threadIdx.x & 63;
  const int half = gw >> 14;
  const int id   = gw & 16383;
  const int b    = id >> 11;
  const int n    = (id >> 8) & 7;
  int h0, w0;
  if (half == 0) { h0 = ((id >> 5) & 7) * 8; w0 = (id & 31) * 2; }
  else           { h0 = ((id >> 3) & 31) * 2; w0 = (id & 7) * 8; }
  const int baseA = qkv_idx(half, b, n, h0, w0);
  const int dWin  = (half == 0) ? 256 : 2048;
  const int baseB = baseA + dWin;

  // ---- QK^T for both windows: lane = (qr, kr) ----
  const int qr = lane >> 3, kr = lane & 7;
  const unsigned short* qA = qkvp + baseA + qr * 32;
  const unsigned short* kA = qkvp + 16777216 + baseA + kr * 32;
  float sA = 0.f, sB = 0.f;
  #pragma unroll
  for (int c = 0; c < 4; ++c) {
    const u32x4 qa = *reinterpret_cast<const u32x4*>(qA + c * 8);
    const u32x4 ka = *reinterpret_cast<const u32x4*>(kA + c * 8);
    const u32x4 qb = *reinterpret_cast<const u32x4*>(qA + dWin + c * 8);
    const u32x4 kb = *reinterpret_cast<const u32x4*>(kA + dWin + c * 8);
    #pragma unroll
    for (int e = 0; e < 4; ++e) {
      sA = __builtin_amdgcn_fdot2(bch2(qa[e]), bch2(ka[e]), sA, false);
      sB = __builtin_amdgcn_fdot2(bch2(qb[e]), bch2(kb[e]), sB, false);
    }
  }
  const float scl = 0.17677669529663687f;
  const float pA = __expf(sA * scl);
  const float pB = __expf(sB * scl);
  float denA = pA, denB = pB;
  denA += __shfl_xor(denA, 1); denA += __shfl_xor(denA, 2); denA += __shfl_xor(denA, 4);
  denB += __shfl_xor(denB, 1); denB += __shfl_xor(denB, 2); denB += __shfl_xor(denB, 4);
  const float aAv = pA * __builtin_amdgcn_rcpf(denA);
  const float aBv = pB * __builtin_amdgcn_rcpf(denB);
  const uint32_t adu = pkrtz_u32(aAv, aBv);   // lo = winA, hi = winB

  // ---- PV: lane = (qr2, win, dgrp); 16B vectors over 8 channels ----
  const int dgrp = lane & 3;
  const int win  = (lane >> 2) & 1;
  const int qr2  = lane >> 3;
  const int d0   = dgrp * 8;
  const int mybase = win ? baseB : baseA;
  const unsigned short* vwin = qkvp + 33554432 + mybase;

  half2v o01 = {0,0}, o23 = {0,0}, o45 = {0,0}, o67 = {0,0};
  #pragma unroll
  for (int k = 0; k < 8; ++k) {
    const uint32_t pairw = (uint32_t)__shfl((int)adu, qr2 * 8 + k);
    const half2v ph = bch2(pairw);
    const _Float16 av = win ? ph.y : ph.x;
    const half2v ak2 = {av, av};
    const u32x4 vv = *reinterpret_cast<const u32x4*>(vwin + k * 32 + d0);
    o01 += ak2 * bch2(vv[0]);
    o23 += ak2 * bch2(vv[1]);
    o45 += ak2 * bch2(vv[2]);
    o67 += ak2 * bch2(vv[3]);
  }

  // ---- LePE: depthwise 3x3 on v (zero-pad SAME) at this lane's pixel ----
  const int hq = (half == 0) ? (h0 + qr2) : (h0 + win);
  const int wq = (half == 0) ? (w0 + win) : (w0 + qr2);
  const unsigned short* vplane = qkvp + 33554432;
  const unsigned short* wl = wlep + half * 2304 + n * 32 + d0;
  half2v l01 = {0,0}, l23 = {0,0}, l45 = {0,0}, l67 = {0,0};
  #pragma unroll
  for (int dy = -1; dy <= 1; ++dy) {
    #pragma unroll
    for (int dx = -1; dx <= 1; ++dx) {
      const int hh = hq + dy, ww = wq + dx;
      u32x4 vv = {0u, 0u, 0u, 0u};
      if ((unsigned)hh < 64u && (unsigned)ww < 64u)
        vv = *reinterpret_cast<const u32x4*>(vplane + qkv_idx(half, b, n, hh, ww) + d0);
      const u32x4 wt = *reinterpret_cast<const u32x4*>(wl + ((dy + 1) * 3 + dx + 1) * 256);
      l01 += bch2(wt[0]) * bch2(vv[0]);
      l23 += bch2(wt[1]) * bch2(vv[1]);
      l45 += bch2(wt[2]) * bch2(vv[2]);
      l67 += bch2(wt[3]) * bch2(vv[3]);
    }
  }

  // ---- store token-major for GEMM2 (16B per lane) ----
  const int m = b * 4096 + hq * 64 + wq;
  const int chan0 = half * 256 + n * 32;
  u32x4 r;
  r[0] = __builtin_bit_cast(uint32_t, (half2v)(o01 + l01));
  r[1] = __builtin_bit_cast(uint32_t, (half2v)(o23 + l23));
  r[2] = __builtin_bit_cast(uint32_t, (half2v)(o45 + l45));
  r[3] = __builtin_bit_cast(uint32_t, (half2v)(o67 + l67));
  *reinterpret_cast<u32x4*>(outp + (size_t)m * 512 + chan0 + d0) = r;
}

// ---------- launch ----------
extern "C" void kernel_launch(void* const* d_in, const int* in_sizes, int n_in,
                              void* d_out, int out_size, void* d_ws, size_t ws_size,
                              hipStream_t stream) {
  const float* x      = (const float*)d_in[0];   // (8, 4096, 512)
  const float* w_qkv  = (const float*)d_in[1];   // (1536, 512)
  const float* w_proj = (const float*)d_in[2];   // (512, 512)
  const float* b_proj = (const float*)d_in[3];   // (512,)
  const float* lepe_h = (const float*)d_in[4];   // (3,3,1,256)
  const float* lepe_v = (const float*)d_in[5];   // (3,3,1,256)
  float* out = (float*)d_out;                    // (8, 4096, 512) f32

  char* ws = (char*)d_ws;
  unsigned short* qkv_p   = (unsigned short*)ws;                 // 96MB: q|k|v window-major
  unsigned short* xh      = (unsigned short*)(ws + 100663296);   // 32MB: x f16; reused as attn_out
  unsigned short* wqkv_h  = (unsigned short*)(ws + 134217728);   // 1536*512 f16
  unsigned short* wproj_h = (unsigned short*)(ws + 135790592);   // 512*512 f16
  unsigned short* wlep_h  = (unsigned short*)(ws + 136314880);   // 2*9*256 f16

  // all casts in one launch
  cvt_all<<<17413, 256, 0, stream>>>(x, w_qkv, w_proj, lepe_h, lepe_v,
                                     xh, wqkv_h, wproj_h, wlep_h);

  // qkv = x @ w_qkv^T -> window-major f16 (persistent 8-phase; 1 block/CU)
  gemm8p<<<256, 512, 0, stream>>>(xh, wqkv_h, qkv_p);

  // stripe attention + LePE -> attn_out token-major (xh dead -> reuse)
  attn_lepe<<<8192, 256, 0, stream>>>(qkv_p, wlep_h, xh);

  // out = attn_out @ w_proj^T + b_proj -> f32 (128^2 2-phase; grid 1024)
  gemm_proj<<<1024, 256, 0, stream>>>(xh, wproj_h, out, b_proj);
}